// Round 19
// baseline (5664.798 us; speedup 1.0000x reference)
//
#include <hip/hip_runtime.h>
#include <cmath>
#include <stdint.h>

#define H_DIM 2048
#define I_DIM 4096
#define N_DIM 16
#define R_DIM 128
#define K_CONV 4
#define L_DIM 8192
#define LC 4096                 // chunk length
#define NCHUNK (L_DIM / LC)
#define SEG 64                  // scan segments per chunk
#define TSEG (LC / SEG)         // 64 steps per segment
#define IN_DIM (I_DIM * N_DIM)  // 65536 recurrences

typedef _Float16 f16x8 __attribute__((ext_vector_type(8)));
typedef _Float16 f16x4v __attribute__((ext_vector_type(4)));
typedef float    f32x4 __attribute__((ext_vector_type(4)));

// direct HBM->LDS, 16B per lane; LDS base must be wave-uniform (HW adds lane*16)
__device__ __forceinline__ void gl_lds(const _Float16* g, _Float16* lbase, int lane) {
#if __has_builtin(__builtin_amdgcn_global_load_lds)
    __builtin_amdgcn_global_load_lds(
        (const __attribute__((address_space(1))) void*)g,
        (__attribute__((address_space(3))) void*)lbase, 16, 0, 0);
#else
    *(f16x8*)&lbase[lane * 8] = *(const f16x8*)g;
#endif
}

// ---------------------------------------------------------------------------
// 256x256 panel GEMM (GEMM1 & GEMM4): A direct global->VGPR (panel layout is
// fragment-ordered), B staged in LDS via 3-buffer counted-vmcnt gl_lds.
// 512 threads = 8 waves (4m x 2n), wave tile 64x128, acc[4][8]. BK=32.
// LDS = 48KB (B only). __launch_bounds__(512, 4): 4 waves/EU = 2 BLOCKS/CU
// (NOTE: 2nd arg is waves per EU, k = w*4/(B/64); round-18's "2" was 1 block).
// Co-resident block's MFMAs hide this block's vmcnt/barrier stalls (m114).
// Steady wait: B(k+1)2 + B(k+2)2 + A(k+1)4 in flight -> vmcnt(8).
// Split-K via blockIdx.y*kchunk, partials at C + y*partStride. OUTF16 store.
// Requires KT = kchunk/32 even and >= 4.
// ---------------------------------------------------------------------------
template <int OUTF16>
__global__ __launch_bounds__(512, 4) void gemm_r256(
    const _Float16* __restrict__ Aph,
    const _Float16* __restrict__ Bph,
    void* __restrict__ Cv, int ldc, int Kd, int gm,
    int kchunk, size_t partStride)
{
    __shared__ __align__(16) _Float16 Bs[3][8192];  // [buf][16 n-panels]

    const int tid = threadIdx.x;
    int bid = blockIdx.x;
    const int q = gridDim.x >> 3;
    bid = (bid & 7) * q + (bid >> 3);    // bijective XCD swizzle (grid % 8 == 0)
    const int m0 = (bid % gm) * 256;
    const int n0 = (bid / gm) * 256;
    const int kbeg = blockIdx.y * kchunk;

    const int w = tid >> 6, l = tid & 63;
    const int wm = w & 3, wn = w >> 2;   // 4m x 2n waves
    const int lr = l & 15, lg = l >> 4;

    const int KP = Kd >> 5;
    const int np0 = n0 >> 4, mp0 = m0 >> 4;

    f32x4 acc[4][8];
#pragma unroll
    for (int a = 0; a < 4; ++a)
#pragma unroll
        for (int b = 0; b < 8; ++b) acc[a][b] = (f32x4){0.f, 0.f, 0.f, 0.f};

    // wave's 4 A row-panels: mp0 + wm*4 + t
    const _Float16* Abase = Aph + ((size_t)(mp0 + wm * 4) * KP) * 512 + (size_t)l * 8;
    const size_t Astride = (size_t)KP * 512;

    f16x8 faA[4], faB[4];

    auto loadA = [&](int k0, f16x8* fa) {
        const size_t ko = (size_t)(k0 >> 5) * 512;
#pragma unroll
        for (int t = 0; t < 4; ++t)
            fa[t] = *(const f16x8*)(Abase + (size_t)t * Astride + ko);
    };
    auto stageB = [&](int k0, int p) {   // 2 gl_lds / thread
        const int kp = k0 >> 5;
#pragma unroll
        for (int s = 0; s < 2; ++s) {
            const int st = w + s * 8;
            gl_lds(Bph + ((size_t)(np0 + st) * KP + kp) * 512 + (size_t)l * 8,
                   &Bs[p][st * 512], l);
        }
    };
    auto domfma = [&](int p, f16x8* fa) {
        f16x8 fb[8];
#pragma unroll
        for (int nt = 0; nt < 8; ++nt)
            fb[nt] = *(const f16x8*)&Bs[p][(wn * 8 + nt) * 512 + l * 8];
        __builtin_amdgcn_s_setprio(1);
#pragma unroll
        for (int mt = 0; mt < 4; ++mt)
#pragma unroll
            for (int nt = 0; nt < 8; ++nt)
                acc[mt][nt] = __builtin_amdgcn_mfma_f32_16x16x32_f16(
                    fa[mt], fb[nt], acc[mt][nt], 0, 0, 0);
        __builtin_amdgcn_s_setprio(0);
    };

    const int KT = kchunk >> 5;          // even, >= 4
    stageB(kbeg, 0);
    stageB(kbeg + 32, 1);
    loadA(kbeg, faA);

    int k = 0;
    for (; k + 3 < KT; k += 2) {
        stageB(kbeg + (k + 2) * 32, (k + 2) % 3);
        loadA(kbeg + (k + 1) * 32, faB);
        asm volatile("s_waitcnt vmcnt(8)" ::: "memory");
        __builtin_amdgcn_s_barrier();
        __builtin_amdgcn_sched_barrier(0);
        domfma(k % 3, faA);
        __builtin_amdgcn_s_barrier();

        stageB(kbeg + (k + 3) * 32, (k + 3) % 3);
        loadA(kbeg + (k + 2) * 32, faA);
        asm volatile("s_waitcnt vmcnt(8)" ::: "memory");
        __builtin_amdgcn_s_barrier();
        __builtin_amdgcn_sched_barrier(0);
        domfma((k + 1) % 3, faB);
        __builtin_amdgcn_s_barrier();
    }
    // k == KT-2
    loadA(kbeg + (KT - 1) * 32, faB);
    asm volatile("s_waitcnt vmcnt(4)" ::: "memory");
    __builtin_amdgcn_s_barrier();
    __builtin_amdgcn_sched_barrier(0);
    domfma((KT - 2) % 3, faA);
    __builtin_amdgcn_s_barrier();
    asm volatile("s_waitcnt vmcnt(0)" ::: "memory");
    __builtin_amdgcn_s_barrier();
    __builtin_amdgcn_sched_barrier(0);
    domfma((KT - 1) % 3, faB);

#pragma unroll
    for (int mt = 0; mt < 4; ++mt) {
        const int row = m0 + wm * 64 + mt * 16 + lg * 4;
#pragma unroll
        for (int nt = 0; nt < 8; ++nt) {
            const int col = n0 + wn * 128 + nt * 16 + lr;
#pragma unroll
            for (int j = 0; j < 4; ++j) {
                if (OUTF16) {
                    _Float16* C = (_Float16*)Cv + (size_t)blockIdx.y * partStride;
                    C[(size_t)(row + j) * ldc + col] = (_Float16)acc[mt][nt][j];
                } else {
                    float* C = (float*)Cv + (size_t)blockIdx.y * partStride;
                    C[(size_t)(row + j) * ldc + col] = acc[mt][nt][j];
                }
            }
        }
    }
}

// ---------------------------------------------------------------------------
// out = P0+P1+P2+P3 (f16 partials, f32 out), 8 elems / thread.
// ---------------------------------------------------------------------------
__global__ __launch_bounds__(256) void reduce4_f16_kernel(
    const _Float16* __restrict__ P, float* __restrict__ out)
{
    const size_t idx = ((size_t)blockIdx.x * 256 + threadIdx.x) * 8;
    const size_t S = (size_t)LC * H_DIM;
    const f16x8 a = *(const f16x8*)(P + idx);
    const f16x8 b = *(const f16x8*)(P + S + idx);
    const f16x8 c = *(const f16x8*)(P + 2 * S + idx);
    const f16x8 d = *(const f16x8*)(P + 3 * S + idx);
    float r[8];
#pragma unroll
    for (int j = 0; j < 8; ++j)
        r[j] = ((float)a[j] + (float)b[j]) + ((float)c[j] + (float)d[j]);
    *(float4*)(out + idx)     = *(float4*)&r[0];
    *(float4*)(out + idx + 4) = *(float4*)&r[4];
}

// ---------------------------------------------------------------------------
// 128x128 panel GEMM (GEMM2/3), 2-buffer schedule.
// AK=0: fp32 A reg-split. AK=3: f16 A rows, hi-only, no cvt (xconv path).
// ASPLIT/BSPLIT lo-correction; OUTF16: store f16 (non-atomic only).
// ---------------------------------------------------------------------------
template <int EPI, int AK, int ASPLIT, int BSPLIT, bool ATOMIC, int OUTF16>
__global__ __launch_bounds__(256, ASPLIT ? 2 : (BSPLIT ? 3 : 4)) void gemm_p(
    const void* __restrict__ Av, int lda,
    const _Float16* __restrict__ Aph,
    const _Float16* __restrict__ Bph, const _Float16* __restrict__ Bpl,
    void* __restrict__ Cv, int ldc,
    int Kd, int Ncap, int gm, int kchunk,
    const float* __restrict__ bias)
{
    constexpr int S_AH = 0;
    constexpr int S_AL = ASPLIT ? 1 : 0;
    constexpr int S_BH = ASPLIT ? 2 : 1;
    constexpr int S_BL = S_BH + 1;
    constexpr int NSLOT = S_BH + 1 + BSPLIT;
    __shared__ __align__(16) _Float16 Sh[2][NSLOT][4096];

    const int tid = threadIdx.x;
    int bid = blockIdx.x;
    const int q = gridDim.x >> 3;
    bid = (bid & 7) * q + (bid >> 3);
    const int m0 = (bid % gm) * 128;
    const int n0 = (bid / gm) * 128;

    const int kbeg = blockIdx.y * kchunk;
    const int kend = (kbeg + kchunk < Kd) ? (kbeg + kchunk) : Kd;

    const int w = tid >> 6, l = tid & 63;
    const int wm = w & 1, wn = w >> 1;
    const int lr = l & 15, lg = l >> 4;

    const int ar = tid >> 1, ah = tid & 1;
    const int aw0 = (ar >> 4) * 512 + (((ah * 2) * 16 + (ar & 15)) * 8);
    const int aw1 = aw0 + 128;

    const int KP = Kd >> 5;
    const int np0 = n0 >> 4;

    f32x4 acc[4][4];
#pragma unroll
    for (int a = 0; a < 4; ++a)
#pragma unroll
        for (int b = 0; b < 4; ++b) acc[a][b] = (f32x4){0.f, 0.f, 0.f, 0.f};

    float xf[16];
    f16x8 sah[2], sal[2];

    auto issueA = [&](int k0) {
        if (AK == 0) {
            const float* Ap = (const float*)Av + (size_t)(m0 + ar) * lda + k0 + ah * 16;
            *(float4*)&xf[0]  = *(const float4*)(Ap + 0);
            *(float4*)&xf[4]  = *(const float4*)(Ap + 4);
            *(float4*)&xf[8]  = *(const float4*)(Ap + 8);
            *(float4*)&xf[12] = *(const float4*)(Ap + 12);
        } else if (AK == 3) {
            const _Float16* Ap = (const _Float16*)Av + (size_t)(m0 + ar) * lda + k0 + ah * 16;
            sah[0] = *(const f16x8*)(Ap + 0);
            sah[1] = *(const f16x8*)(Ap + 8);
        }
    };
    auto cvtA = [&]() {
        if (AK == 0) {
#pragma unroll
            for (int c2 = 0; c2 < 2; ++c2)
#pragma unroll
                for (int j = 0; j < 8; ++j) {
                    const float xv = xf[c2 * 8 + j];
                    const _Float16 h = (_Float16)xv;
                    sah[c2][j] = h;
                    if (ASPLIT) sal[c2][j] = (_Float16)(xv - (float)h);
                }
        }
    };
    auto writeA = [&](int p) {
        *(f16x8*)&Sh[p][S_AH][aw0] = sah[0];
        *(f16x8*)&Sh[p][S_AH][aw1] = sah[1];
        if (ASPLIT) {
            *(f16x8*)&Sh[p][S_AL][aw0] = sal[0];
            *(f16x8*)&Sh[p][S_AL][aw1] = sal[1];
        }
    };
    auto stageGL = [&](int k0, int p) {
        const int kp = k0 >> 5;
#pragma unroll
        for (int qq = 0; qq < 2; ++qq) {
            const int st = 2 * w + qq;
            const size_t go = ((size_t)(np0 + st) * KP + kp) * 512 + (size_t)l * 8;
            gl_lds(Bph + go, &Sh[p][S_BH][st * 512], l);
            if (BSPLIT) gl_lds(Bpl + go, &Sh[p][S_BL][st * 512], l);
        }
    };
    auto domfma = [&](int b) {
        f16x8 fah[4], fal[4], fbh[4], fbl[4];
#pragma unroll
        for (int t = 0; t < 4; ++t) {
            fah[t] = *(const f16x8*)&Sh[b][S_AH][(wm * 4 + t) * 512 + l * 8];
            if (ASPLIT) fal[t] = *(const f16x8*)&Sh[b][S_AL][(wm * 4 + t) * 512 + l * 8];
            fbh[t] = *(const f16x8*)&Sh[b][S_BH][(wn * 4 + t) * 512 + l * 8];
            if (BSPLIT) fbl[t] = *(const f16x8*)&Sh[b][S_BL][(wn * 4 + t) * 512 + l * 8];
        }
        __builtin_amdgcn_s_setprio(1);
#pragma unroll
        for (int mt = 0; mt < 4; ++mt)
#pragma unroll
            for (int nt = 0; nt < 4; ++nt) {
                f32x4& a = acc[mt][nt];
                a = __builtin_amdgcn_mfma_f32_16x16x32_f16(fah[mt], fbh[nt], a, 0, 0, 0);
                if (BSPLIT)
                    a = __builtin_amdgcn_mfma_f32_16x16x32_f16(fah[mt], fbl[nt], a, 0, 0, 0);
                if (ASPLIT)
                    a = __builtin_amdgcn_mfma_f32_16x16x32_f16(fal[mt], fbh[nt], a, 0, 0, 0);
            }
        __builtin_amdgcn_s_setprio(0);
    };

    issueA(kbeg); cvtA(); writeA(0);
    stageGL(kbeg, 0);
    __syncthreads();
    int p = 0;
    for (int k0 = kbeg; k0 < kend; k0 += 32) {
        const bool more = (k0 + 32 < kend);
        if (more) {
            issueA(k0 + 32);
            stageGL(k0 + 32, p ^ 1);
        }
        domfma(p);
        if (more) { cvtA(); writeA(p ^ 1); }
        __syncthreads();
        p ^= 1;
    }

#pragma unroll
    for (int mt = 0; mt < 4; ++mt) {
        const int row = m0 + wm * 64 + mt * 16 + lg * 4;
#pragma unroll
        for (int nt = 0; nt < 4; ++nt) {
            const int col = n0 + wn * 64 + nt * 16 + lr;
            if (Ncap == 0 || col < Ncap) {
#pragma unroll
                for (int j = 0; j < 4; ++j) {
                    float v = acc[mt][nt][j];
                    if (EPI == 1) {
                        v += bias[col];
                        v = (v > 20.f) ? v : __logf(1.f + __expf(v));
                    }
                    const size_t off = (size_t)(row + j) * ldc + col;
                    if (ATOMIC)      atomicAdd(&((float*)Cv)[off], v);
                    else if (OUTF16) ((_Float16*)Cv)[off] = (_Float16)v;
                    else             ((float*)Cv)[off] = v;
                }
            }
        }
    }
}

// ---------------------------------------------------------------------------
// Pack W [Kd][Nd] fp32 -> f16 B-panels [Nd/16][Kd/32][512]; lo only if Pl.
// ---------------------------------------------------------------------------
__global__ __launch_bounds__(128) void pack_bp(
    const float* __restrict__ W, _Float16* __restrict__ Ph,
    _Float16* __restrict__ Pl, int Kd, int Nd)
{
    __shared__ float t[32][33];
    const int tid = threadIdx.x;
    const int n0 = blockIdx.x * 32, k0 = blockIdx.y * 32;
#pragma unroll
    for (int h = 0; h < 2; ++h) {
        const int qd = tid + h * 128;
        const int kk = qd >> 3, qq = qd & 7;
        *(float4*)&t[kk][qq * 4] = *(const float4*)(W + (size_t)(k0 + kk) * Nd + n0 + qq * 4);
    }
    __syncthreads();
    const int c = tid >> 5, nn = tid & 31;
    const int np = (n0 + nn) >> 4;
    const int r  = nn & 15;
    const int kp = k0 >> 5;
    const size_t base = ((size_t)np * (Kd >> 5) + kp) * 512 + (c * 16 + r) * 8;
    f16x8 vh, vl;
#pragma unroll
    for (int j = 0; j < 8; ++j) {
        const float v = t[c * 8 + j][nn];
        const _Float16 h = (_Float16)v;
        vh[j] = h;
        vl[j] = (_Float16)(v - (float)h);
    }
    *(f16x8*)&Ph[base] = vh;
    if (Pl) *(f16x8*)&Pl[base] = vl;
}

// ---------------------------------------------------------------------------
// Pack A fp32 [M][K] row-major -> hi f16 A-panels [M/16][K/32][512].
// ---------------------------------------------------------------------------
__global__ __launch_bounds__(256) void pack_ap(
    const float* __restrict__ A, int lda,
    _Float16* __restrict__ Ph, int Kd)
{
    const int tid = threadIdx.x;
    const int mp = blockIdx.x;
    const int r = tid >> 4, c8 = tid & 15;
    const int k0 = blockIdx.y * 128 + c8 * 8;
    const float* Ap = A + (size_t)(mp * 16 + r) * lda + k0;
    const float4 v0 = *(const float4*)Ap;
    const float4 v1 = *(const float4*)(Ap + 4);
    const float x[8] = {v0.x, v0.y, v0.z, v0.w, v1.x, v1.y, v1.z, v1.w};
    f16x8 vh;
#pragma unroll
    for (int j = 0; j < 8; ++j) vh[j] = (_Float16)x[j];
    const int kp = k0 >> 5;
    const int c  = (k0 >> 3) & 3;
    const size_t base = ((size_t)mp * (Kd >> 5) + kp) * 512 + (c * 16 + r) * 8;
    *(f16x8*)&Ph[base] = vh;
}

// ---------------------------------------------------------------------------
// Causal depthwise conv (K=4) + bias + silu (4ch x 8t / thread); zeroes ssm.
// proj (x-half) f16 ld 2I; xconv written f16. Tail saved f32.
// ---------------------------------------------------------------------------
__global__ __launch_bounds__(256) void conv_silu_kernel(
    const _Float16* __restrict__ proj,
    const float* __restrict__ xtail_in,
    float* __restrict__ xtail_out,
    const float* __restrict__ w,
    const float* __restrict__ b,
    _Float16* __restrict__ xconv,
    float* __restrict__ ssm,
    int first)
{
    const int gid = blockIdx.x * 256 + threadIdx.x;
    if (gid < (LC * 160) / 4)
        *(float4*)(ssm + (size_t)gid * 4) = make_float4(0.f, 0.f, 0.f, 0.f);

    const int i4 = gid & (I_DIM / 4 - 1);
    const int t8 = gid >> 10;
    const int i = i4 * 4;
    const int tt0 = t8 * 8;

    const float4 w0 = *(const float4*)(w + (size_t)(i + 0) * 4);
    const float4 w1 = *(const float4*)(w + (size_t)(i + 1) * 4);
    const float4 w2 = *(const float4*)(w + (size_t)(i + 2) * 4);
    const float4 w3 = *(const float4*)(w + (size_t)(i + 3) * 4);
    const float4 bb = *(const float4*)(b + i);

    auto ldrow = [&](int row) -> float4 {
        const f16x4v v = *(const f16x4v*)(proj + (size_t)row * (2 * I_DIM) + i);
        return make_float4((float)v[0], (float)v[1], (float)v[2], (float)v[3]);
    };

    float4 r[11];
    if (tt0 >= 3) {
#pragma unroll
        for (int s = 0; s < 11; ++s) r[s] = ldrow(tt0 - 3 + s);
    } else {
#pragma unroll
        for (int s = 0; s < 3; ++s)
            r[s] = first ? make_float4(0.f, 0.f, 0.f, 0.f)
                         : *(const float4*)(xtail_in + (size_t)s * I_DIM + i);
#pragma unroll
        for (int s = 3; s < 11; ++s) r[s] = ldrow(tt0 - 3 + s);
    }

#pragma unroll
    for (int s = 0; s < 8; ++s) {
        float4 y = bb;
        y.x = fmaf(w0.x, r[s].x, y.x); y.x = fmaf(w0.y, r[s+1].x, y.x);
        y.x = fmaf(w0.z, r[s+2].x, y.x); y.x = fmaf(w0.w, r[s+3].x, y.x);
        y.y = fmaf(w1.x, r[s].y, y.y); y.y = fmaf(w1.y, r[s+1].y, y.y);
        y.y = fmaf(w1.z, r[s+2].y, y.y); y.y = fmaf(w1.w, r[s+3].y, y.y);
        y.z = fmaf(w2.x, r[s].z, y.z); y.z = fmaf(w2.y, r[s+1].z, y.z);
        y.z = fmaf(w2.z, r[s+2].z, y.z); y.z = fmaf(w2.w, r[s+3].z, y.z);
        y.w = fmaf(w3.x, r[s].w, y.w); y.w = fmaf(w3.y, r[s+1].w, y.w);
        y.w = fmaf(w3.z, r[s+2].w, y.w); y.w = fmaf(w3.w, r[s+3].w, y.w);
        y.x = y.x / (1.f + __expf(-y.x));
        y.y = y.y / (1.f + __expf(-y.y));
        y.z = y.z / (1.f + __expf(-y.z));
        y.w = y.w / (1.f + __expf(-y.w));
        f16x4v o;
        o[0] = (_Float16)y.x; o[1] = (_Float16)y.y;
        o[2] = (_Float16)y.z; o[3] = (_Float16)y.w;
        *(f16x4v*)(xconv + (size_t)(tt0 + s) * I_DIM + i) = o;
    }

    if (tt0 == LC - 8) {
#pragma unroll
        for (int qq = 0; qq < 3; ++qq)
            *(float4*)(xtail_out + (size_t)qq * I_DIM + i) = r[8 + qq];
    }
}

// ---------------------------------------------------------------------------
// Segment-parallel scan. delta/gate f16 (ld 2I); u (xc) f16.
// ---------------------------------------------------------------------------
__global__ __launch_bounds__(256) void scan_part1(
    const _Float16* __restrict__ delta,
    const float* __restrict__ ssm,
    const _Float16* __restrict__ xc,
    const float* __restrict__ A_log,
    float* __restrict__ aprod,
    float* __restrict__ hend)
{
    __shared__ float Bs[TSEG][16];
    const int tid = threadIdx.x;
    const int i = blockIdx.x * 128 + (tid >> 1);
    const int half = tid & 1;
    const int seg = blockIdx.y;
    const int t0 = seg * TSEG;

    {
        const int tt = tid >> 2, c = (tid & 3) * 4;
        *(float4*)&Bs[tt][c] = *(const float4*)&ssm[(size_t)(t0 + tt) * 160 + 128 + c];
    }
    __syncthreads();

    float Ai[8], h[8], ap[8];
    {
        const float4 a0 = *(const float4*)&A_log[(size_t)i * 16 + half * 8];
        const float4 a1 = *(const float4*)&A_log[(size_t)i * 16 + half * 8 + 4];
        const float al[8] = {a0.x, a0.y, a0.z, a0.w, a1.x, a1.y, a1.z, a1.w};
#pragma unroll
        for (int n = 0; n < 8; ++n) { Ai[n] = -expf(al[n]); h[n] = 0.f; ap[n] = 1.f; }
    }

    float d0 = (float)delta[(size_t)t0 * (2 * I_DIM) + i];
    float u0 = (float)xc[(size_t)t0 * I_DIM + i];
    float d1 = (float)delta[(size_t)(t0 + 1) * (2 * I_DIM) + i];
    float u1 = (float)xc[(size_t)(t0 + 1) * I_DIM + i];
    for (int t = 0; t < TSEG; t += 2) {
        float d2 = 0.f, u2 = 0.f, d3 = 0.f, u3 = 0.f;
        if (t + 3 < TSEG) {
            d2 = (float)delta[(size_t)(t0 + t + 2) * (2 * I_DIM) + i];
            u2 = (float)xc[(size_t)(t0 + t + 2) * I_DIM + i];
            d3 = (float)delta[(size_t)(t0 + t + 3) * (2 * I_DIM) + i];
            u3 = (float)xc[(size_t)(t0 + t + 3) * I_DIM + i];
        }
        {
            const float du = d0 * u0;
#pragma unroll
            for (int n = 0; n < 8; ++n) {
                const float a = __expf(d0 * Ai[n]);
                h[n] = fmaf(h[n], a, du * Bs[t][half * 8 + n]);
                ap[n] *= a;
            }
        }
        {
            const float du = d1 * u1;
#pragma unroll
            for (int n = 0; n < 8; ++n) {
                const float a = __expf(d1 * Ai[n]);
                h[n] = fmaf(h[n], a, du * Bs[t + 1][half * 8 + n]);
                ap[n] *= a;
            }
        }
        d0 = d2; u0 = u2; d1 = d3; u1 = u3;
    }

    const size_t base = (size_t)seg * IN_DIM + (size_t)i * 16 + half * 8;
#pragma unroll
    for (int qq = 0; qq < 2; ++qq) {
        float4 va = {ap[qq * 4 + 0], ap[qq * 4 + 1], ap[qq * 4 + 2], ap[qq * 4 + 3]};
        float4 vh = {h[qq * 4 + 0], h[qq * 4 + 1], h[qq * 4 + 2], h[qq * 4 + 3]};
        *(float4*)&aprod[base + qq * 4] = va;
        *(float4*)&hend[base + qq * 4]  = vh;
    }
}

__global__ __launch_bounds__(256) void scan_part2(
    const float* __restrict__ aprod,
    float* __restrict__ hend,
    float* __restrict__ hstate,
    int first)
{
    const int gid = blockIdx.x * 256 + threadIdx.x;
    float h = first ? 0.f : hstate[gid];
    for (int s = 0; s < SEG; ++s) {
        const size_t idx = (size_t)s * IN_DIM + gid;
        const float ap = aprod[idx];
        const float he = hend[idx];
        hend[idx] = h;
        h = fmaf(ap, h, he);
    }
    hstate[gid] = h;
}

// Phase 3: re-run segment from h_start; z (f16) written in GEMM4 A-panel layout.
__global__ __launch_bounds__(256) void scan_part3(
    const _Float16* __restrict__ delta,
    const _Float16* __restrict__ gate,
    const float* __restrict__ ssm,
    const _Float16* __restrict__ xc,
    _Float16* __restrict__ zPh,
    const float* __restrict__ A_log,
    const float* __restrict__ Dp,
    const float* __restrict__ hstart)  // [SEG][I][N]
{
    __shared__ float BCs[TSEG][32];
    const int tid = threadIdx.x;
    const int i = blockIdx.x * 128 + (tid >> 1);
    const int half = tid & 1;
    const int seg = blockIdx.y;
    const int t0 = seg * TSEG;

    {
        const int tt = tid >> 2, c = (tid & 3) * 8;
        *(float4*)&BCs[tt][c]     = *(const float4*)&ssm[(size_t)(t0 + tt) * 160 + 128 + c];
        *(float4*)&BCs[tt][c + 4] = *(const float4*)&ssm[(size_t)(t0 + tt) * 160 + 132 + c];
    }
    __syncthreads();

    float Ai[8], h[8];
    {
        const float4 a0 = *(const float4*)&A_log[(size_t)i * 16 + half * 8];
        const float4 a1 = *(const float4*)&A_log[(size_t)i * 16 + half * 8 + 4];
        const float al[8] = {a0.x, a0.y, a0.z, a0.w, a1.x, a1.y, a1.z, a1.w};
#pragma unroll
        for (int n = 0; n < 8; ++n) Ai[n] = -expf(al[n]);
        const size_t base = (size_t)seg * IN_DIM + (size_t)i * 16 + half * 8;
        const float4 h0 = *(const float4*)&hstart[base];
        const float4 h1 = *(const float4*)&hstart[base + 4];
        h[0] = h0.x; h[1] = h0.y; h[2] = h0.z; h[3] = h0.w;
        h[4] = h1.x; h[5] = h1.y; h[6] = h1.z; h[7] = h1.w;
    }
    const float Di = Dp[i];

    const int kp = i >> 5, cc = (i >> 3) & 3, jj = i & 7;
    const size_t zb = (size_t)kp * 512 + (size_t)cc * 128 + jj;

    float d0 = (float)delta[(size_t)t0 * (2 * I_DIM) + i];
    float u0 = (float)xc[(size_t)t0 * I_DIM + i];
    float g0 = (float)gate[(size_t)t0 * (2 * I_DIM) + i];
    float d1 = (float)delta[(size_t)(t0 + 1) * (2 * I_DIM) + i];
    float u1 = (float)xc[(size_t)(t0 + 1) * I_DIM + i];
    float g1 = (float)gate[(size_t)(t0 + 1) * (2 * I_DIM) + i];
    for (int t = 0; t < TSEG; t += 2) {
        float d2 = 0.f, u2 = 0.f, g2 = 0.f, d3 = 0.f, u3 = 0.f, g3 = 0.f;
        if (t + 3 < TSEG) {
            d2 = (float)delta[(size_t)(t0 + t + 2) * (2 * I_DIM) + i];
            u2 = (float)xc[(size_t)(t0 + t + 2) * I_DIM + i];
            g2 = (float)gate[(size_t)(t0 + t + 2) * (2 * I_DIM) + i];
            d3 = (float)delta[(size_t)(t0 + t + 3) * (2 * I_DIM) + i];
            u3 = (float)xc[(size_t)(t0 + t + 3) * I_DIM + i];
            g3 = (float)gate[(size_t)(t0 + t + 3) * (2 * I_DIM) + i];
        }
#pragma unroll
        for (int ss = 0; ss < 2; ++ss) {
            const float d = ss ? d1 : d0;
            const float u = ss ? u1 : u0;
            const float g = ss ? g1 : g0;
            const int tt = t + ss;
            const float du = d * u;
            float y = 0.f;
#pragma unroll
            for (int n = 0; n < 8; ++n) {
                const float a = __expf(d * Ai[n]);
                h[n] = fmaf(h[n], a, du * BCs[tt][half * 8 + n]);
                y = fmaf(h[n], BCs[tt][16 + half * 8 + n], y);
            }
            y += __shfl_xor(y, 1);
            if (half == 0) {
                const float sg = g / (1.f + __expf(-g));
                const float zv = (y + u * Di) * sg;
                const int row = t0 + tt;
                zPh[((size_t)(row >> 4) * (I_DIM >> 5)) * 512 + zb + (size_t)(row & 15) * 8]
                    = (_Float16)zv;
            }
        }
        d0 = d2; u0 = u2; g0 = g2; d1 = d3; u1 = u3; g1 = g3;
    }
}

// ---------------------------------------------------------------------------
extern "C" void kernel_launch(void* const* d_in, const int* in_sizes, int n_in,
                              void* d_out, int out_size, void* d_ws, size_t ws_size,
                              hipStream_t stream)
{
    const float* hs      = (const float*)d_in[0];
    const float* W_in    = (const float*)d_in[1];
    const float* conv_w  = (const float*)d_in[2];
    const float* conv_b  = (const float*)d_in[3];
    const float* W_x     = (const float*)d_in[4];
    const float* W_dt    = (const float*)d_in[5];
    const float* dt_bias = (const float*)d_in[6];
    const float* A_log   = (const float*)d_in[7];
    const float* Dp      = (const float*)d_in[8];
    const float* W_out   = (const float*)d_in[9];
    float* out = (float*)d_out;

    // workspace layout (~223 MB)
    char* p = (char*)d_ws;
    auto alloc = [&](size_t bytes) {
        char* r = p;
        p += (bytes + 255) & ~(size_t)255;
        return r;
    };
    _Float16* proj16 = (_Float16*)alloc((size_t)68 * 1024 * 1024);
    _Float16* xconv16 = (_Float16*)alloc((size_t)LC * I_DIM * 2);  // 32 MB
    float* ssm    = (float*)alloc((size_t)LC * 160 * 4);           // 2.6 MB
    float* xtail  = (float*)alloc((size_t)2 * 3 * I_DIM * 4);
    float* hstate = (float*)alloc((size_t)IN_DIM * 4);
    _Float16* WinPh  = (_Float16*)alloc((size_t)2 * I_DIM * H_DIM * 2);  // 32 MB
    _Float16* WoutPh = (_Float16*)alloc((size_t)H_DIM * I_DIM * 2);      // 16 MB
    _Float16* WdtPh  = (_Float16*)alloc((size_t)I_DIM * R_DIM * 2);
    _Float16* WdtPl  = (_Float16*)alloc((size_t)I_DIM * R_DIM * 2);
    _Float16* WxPh   = (_Float16*)alloc((size_t)256 * I_DIM * 2);
    _Float16* WxPl   = (_Float16*)alloc((size_t)256 * I_DIM * 2);
    _Float16* hsPh   = (_Float16*)alloc((size_t)L_DIM * H_DIM * 2);  // 33.5 MB
    _Float16* zPh    = (_Float16*)alloc((size_t)LC * I_DIM * 2);     // 32 MB

    const dim3 blk(256);
    const int NSSM = R_DIM + 2 * N_DIM;  // 160

    // ---- pack weights + full hs into panel format (once per launch) ----
    pack_bp<<<dim3(2 * I_DIM / 32, H_DIM / 32), dim3(128), 0, stream>>>(
        W_in, WinPh, nullptr, H_DIM, 2 * I_DIM);
    pack_bp<<<dim3(H_DIM / 32, I_DIM / 32), dim3(128), 0, stream>>>(
        W_out, WoutPh, nullptr, I_DIM, H_DIM);
    pack_bp<<<dim3(I_DIM / 32, R_DIM / 32), dim3(128), 0, stream>>>(
        W_dt, WdtPh, WdtPl, R_DIM, I_DIM);
    pack_bp<<<dim3(NSSM / 32, I_DIM / 32), dim3(128), 0, stream>>>(
        W_x, WxPh, WxPl, I_DIM, NSSM);
    pack_ap<<<dim3(L_DIM / 16, H_DIM / 128), blk, 0, stream>>>(
        hs, H_DIM, hsPh, H_DIM);

    for (int c = 0; c < NCHUNK; ++c) {
        const int t0 = c * LC;
        const int first = (c == 0) ? 1 : 0;
        float* out_c = out + (size_t)t0 * H_DIM;
        float* aprod = out_c;                 // scan scratch in out region
        float* hend  = out_c + (size_t)SEG * IN_DIM;  // exact fit: 2*SEG*IN = LC*H
        float* xtA = xtail + (size_t)(c & 1) * 3 * I_DIM;
        float* xtB = xtail + (size_t)((c & 1) ^ 1) * 3 * I_DIM;
        const _Float16* hsPh_c = hsPh + (size_t)(t0 >> 4) * (H_DIM >> 5) * 512;

        // 1) proj(f16) = hs_c @ W_in  (512 blocks, 2 blocks/CU)
        gemm_r256<1><<<dim3(512, 1), dim3(512), 0, stream>>>(
            hsPh_c, WinPh, proj16, 2 * I_DIM, H_DIM, LC / 256, H_DIM, 0);

        // 2) xconv(f16) = silu(dwconv(x_pre) + b); zeroes ssm; saves tail
        conv_silu_kernel<<<dim3((LC / 8) * (I_DIM / 4) / 256), blk, 0, stream>>>(
            proj16, xtA, xtB, conv_w, conv_b, xconv16, ssm, first);

        // 3) ssm = xconv @ W_x  (f16 A direct, B split, split-K x8, atomics)
        gemm_p<0, 3, 0, 1, true, 0><<<dim3(2 * (LC / 128), 8), blk, 0, stream>>>(
            xconv16, I_DIM, nullptr, WxPh, WxPl, ssm, NSSM,
            I_DIM, NSSM, LC / 128, I_DIM / 8, nullptr);

        // 4) delta(f16) = softplus(ssm[:, :R] @ W_dt + dt_bias) -> proj x-half
        gemm_p<1, 0, 1, 1, false, 1><<<dim3(32 * (LC / 128), 1), blk, 0, stream>>>(
            ssm, NSSM, nullptr, WdtPh, WdtPl, proj16, 2 * I_DIM,
            R_DIM, 0, LC / 128, R_DIM, dt_bias);

        // 5) segment-parallel scan; z -> zPh panels
        scan_part1<<<dim3(I_DIM / 128, SEG), blk, 0, stream>>>(
            proj16, ssm, xconv16, A_log, aprod, hend);
        scan_part2<<<dim3(IN_DIM / 256), blk, 0, stream>>>(
            aprod, hend, hstate, first);
        scan_part3<<<dim3(I_DIM / 128, SEG), blk, 0, stream>>>(
            proj16, proj16 + I_DIM, ssm, xconv16, zPh, A_log, Dp, hend);

        // 6) GEMM4 partials (f16): 4 k-slices of z @ W_out into proj region
        gemm_r256<1><<<dim3((LC / 256) * (H_DIM / 256), 4), dim3(512), 0, stream>>>(
            zPh, WoutPh, proj16, H_DIM, I_DIM, LC / 256,
            I_DIM / 4, (size_t)LC * H_DIM);

        // 7) out_c = P0+P1+P2+P3
        reduce4_f16_kernel<<<dim3(LC * H_DIM / 2048), blk, 0, stream>>>(
            proj16, out_c);
    }
}

// Round 20
// 1011.385 us; speedup vs baseline: 5.6010x; 5.6010x over previous
//
#include <hip/hip_runtime.h>
#include <cmath>
#include <stdint.h>

#define H_DIM 2048
#define I_DIM 4096
#define N_DIM 16
#define R_DIM 128
#define K_CONV 4
#define L_DIM 8192
#define LC 4096                 // chunk length
#define NCHUNK (L_DIM / LC)
#define SEG 64                  // scan segments per chunk
#define TSEG (LC / SEG)         // 64 steps per segment
#define IN_DIM (I_DIM * N_DIM)  // 65536 recurrences

typedef _Float16 f16x8 __attribute__((ext_vector_type(8)));
typedef _Float16 f16x4v __attribute__((ext_vector_type(4)));
typedef float    f32x4 __attribute__((ext_vector_type(4)));

// direct HBM->LDS, 16B per lane; LDS base must be wave-uniform (HW adds lane*16)
__device__ __forceinline__ void gl_lds(const _Float16* g, _Float16* lbase, int lane) {
#if __has_builtin(__builtin_amdgcn_global_load_lds)
    __builtin_amdgcn_global_load_lds(
        (const __attribute__((address_space(1))) void*)g,
        (__attribute__((address_space(3))) void*)lbase, 16, 0, 0);
#else
    *(f16x8*)&lbase[lane * 8] = *(const f16x8*)g;
#endif
}

// ---------------------------------------------------------------------------
// 256x256 panel GEMM (GEMM1 & GEMM4): A direct global->VGPR (panel layout is
// fragment-ordered), B staged in LDS via 3-buffer counted-vmcnt gl_lds.
// 512 threads = 8 waves (4m x 2n), wave tile 64x128, acc[4][8]. BK=32.
// LDS = 48KB. launch_bounds(512,2): acc[4][8] needs >=160 VGPR, so 1 block/CU
// is the max; (512,4) forces 64 VGPR and spills the accumulator (round-19:
// 8.6 GB scratch traffic/dispatch, 5.6ms total). Do NOT raise this.
// Steady wait: B(k+1)2 + B(k+2)2 + A(k+1)4 in flight -> vmcnt(8).
// Split-K via blockIdx.y*kchunk, partials at C + y*partStride. OUTF16 store.
// Requires KT = kchunk/32 even and >= 4.
// ---------------------------------------------------------------------------
template <int OUTF16>
__global__ __launch_bounds__(512, 2) void gemm_r256(
    const _Float16* __restrict__ Aph,
    const _Float16* __restrict__ Bph,
    void* __restrict__ Cv, int ldc, int Kd, int gm,
    int kchunk, size_t partStride)
{
    __shared__ __align__(16) _Float16 Bs[3][8192];  // [buf][16 n-panels]

    const int tid = threadIdx.x;
    int bid = blockIdx.x;
    const int q = gridDim.x >> 3;
    bid = (bid & 7) * q + (bid >> 3);    // bijective XCD swizzle (grid % 8 == 0)
    const int m0 = (bid % gm) * 256;
    const int n0 = (bid / gm) * 256;
    const int kbeg = blockIdx.y * kchunk;

    const int w = tid >> 6, l = tid & 63;
    const int wm = w & 3, wn = w >> 2;   // 4m x 2n waves
    const int lr = l & 15, lg = l >> 4;

    const int KP = Kd >> 5;
    const int np0 = n0 >> 4, mp0 = m0 >> 4;

    f32x4 acc[4][8];
#pragma unroll
    for (int a = 0; a < 4; ++a)
#pragma unroll
        for (int b = 0; b < 8; ++b) acc[a][b] = (f32x4){0.f, 0.f, 0.f, 0.f};

    // wave's 4 A row-panels: mp0 + wm*4 + t
    const _Float16* Abase = Aph + ((size_t)(mp0 + wm * 4) * KP) * 512 + (size_t)l * 8;
    const size_t Astride = (size_t)KP * 512;

    f16x8 faA[4], faB[4];

    auto loadA = [&](int k0, f16x8* fa) {
        const size_t ko = (size_t)(k0 >> 5) * 512;
#pragma unroll
        for (int t = 0; t < 4; ++t)
            fa[t] = *(const f16x8*)(Abase + (size_t)t * Astride + ko);
    };
    auto stageB = [&](int k0, int p) {   // 2 gl_lds / thread
        const int kp = k0 >> 5;
#pragma unroll
        for (int s = 0; s < 2; ++s) {
            const int st = w + s * 8;
            gl_lds(Bph + ((size_t)(np0 + st) * KP + kp) * 512 + (size_t)l * 8,
                   &Bs[p][st * 512], l);
        }
    };
    auto domfma = [&](int p, f16x8* fa) {
        f16x8 fb[8];
#pragma unroll
        for (int nt = 0; nt < 8; ++nt)
            fb[nt] = *(const f16x8*)&Bs[p][(wn * 8 + nt) * 512 + l * 8];
        __builtin_amdgcn_s_setprio(1);
#pragma unroll
        for (int mt = 0; mt < 4; ++mt)
#pragma unroll
            for (int nt = 0; nt < 8; ++nt)
                acc[mt][nt] = __builtin_amdgcn_mfma_f32_16x16x32_f16(
                    fa[mt], fb[nt], acc[mt][nt], 0, 0, 0);
        __builtin_amdgcn_s_setprio(0);
    };

    const int KT = kchunk >> 5;          // even, >= 4
    stageB(kbeg, 0);
    stageB(kbeg + 32, 1);
    loadA(kbeg, faA);

    int k = 0;
    for (; k + 3 < KT; k += 2) {
        stageB(kbeg + (k + 2) * 32, (k + 2) % 3);
        loadA(kbeg + (k + 1) * 32, faB);
        asm volatile("s_waitcnt vmcnt(8)" ::: "memory");
        __builtin_amdgcn_s_barrier();
        __builtin_amdgcn_sched_barrier(0);
        domfma(k % 3, faA);
        __builtin_amdgcn_s_barrier();

        stageB(kbeg + (k + 3) * 32, (k + 3) % 3);
        loadA(kbeg + (k + 2) * 32, faA);
        asm volatile("s_waitcnt vmcnt(8)" ::: "memory");
        __builtin_amdgcn_s_barrier();
        __builtin_amdgcn_sched_barrier(0);
        domfma((k + 1) % 3, faB);
        __builtin_amdgcn_s_barrier();
    }
    // k == KT-2
    loadA(kbeg + (KT - 1) * 32, faB);
    asm volatile("s_waitcnt vmcnt(4)" ::: "memory");
    __builtin_amdgcn_s_barrier();
    __builtin_amdgcn_sched_barrier(0);
    domfma((KT - 2) % 3, faA);
    __builtin_amdgcn_s_barrier();
    asm volatile("s_waitcnt vmcnt(0)" ::: "memory");
    __builtin_amdgcn_s_barrier();
    __builtin_amdgcn_sched_barrier(0);
    domfma((KT - 1) % 3, faB);

#pragma unroll
    for (int mt = 0; mt < 4; ++mt) {
        const int row = m0 + wm * 64 + mt * 16 + lg * 4;
#pragma unroll
        for (int nt = 0; nt < 8; ++nt) {
            const int col = n0 + wn * 128 + nt * 16 + lr;
#pragma unroll
            for (int j = 0; j < 4; ++j) {
                if (OUTF16) {
                    _Float16* C = (_Float16*)Cv + (size_t)blockIdx.y * partStride;
                    C[(size_t)(row + j) * ldc + col] = (_Float16)acc[mt][nt][j];
                } else {
                    float* C = (float*)Cv + (size_t)blockIdx.y * partStride;
                    C[(size_t)(row + j) * ldc + col] = acc[mt][nt][j];
                }
            }
        }
    }
}

// ---------------------------------------------------------------------------
// out = P0+P1+P2+P3 (f16 partials, f32 out), 8 elems / thread.
// ---------------------------------------------------------------------------
__global__ __launch_bounds__(256) void reduce4_f16_kernel(
    const _Float16* __restrict__ P, float* __restrict__ out)
{
    const size_t idx = ((size_t)blockIdx.x * 256 + threadIdx.x) * 8;
    const size_t S = (size_t)LC * H_DIM;
    const f16x8 a = *(const f16x8*)(P + idx);
    const f16x8 b = *(const f16x8*)(P + S + idx);
    const f16x8 c = *(const f16x8*)(P + 2 * S + idx);
    const f16x8 d = *(const f16x8*)(P + 3 * S + idx);
    float r[8];
#pragma unroll
    for (int j = 0; j < 8; ++j)
        r[j] = ((float)a[j] + (float)b[j]) + ((float)c[j] + (float)d[j]);
    *(float4*)(out + idx)     = *(float4*)&r[0];
    *(float4*)(out + idx + 4) = *(float4*)&r[4];
}

// ---------------------------------------------------------------------------
// 128x128 panel GEMM (GEMM2/3), 2-buffer schedule.
// AK=0: fp32 A reg-split. AK=3: f16 A rows, hi-only, no cvt (xconv path).
// ASPLIT/BSPLIT lo-correction; OUTF16: store f16 (non-atomic only).
// ---------------------------------------------------------------------------
template <int EPI, int AK, int ASPLIT, int BSPLIT, bool ATOMIC, int OUTF16>
__global__ __launch_bounds__(256, ASPLIT ? 2 : (BSPLIT ? 3 : 4)) void gemm_p(
    const void* __restrict__ Av, int lda,
    const _Float16* __restrict__ Aph,
    const _Float16* __restrict__ Bph, const _Float16* __restrict__ Bpl,
    void* __restrict__ Cv, int ldc,
    int Kd, int Ncap, int gm, int kchunk,
    const float* __restrict__ bias)
{
    constexpr int S_AH = 0;
    constexpr int S_AL = ASPLIT ? 1 : 0;
    constexpr int S_BH = ASPLIT ? 2 : 1;
    constexpr int S_BL = S_BH + 1;
    constexpr int NSLOT = S_BH + 1 + BSPLIT;
    __shared__ __align__(16) _Float16 Sh[2][NSLOT][4096];

    const int tid = threadIdx.x;
    int bid = blockIdx.x;
    const int q = gridDim.x >> 3;
    bid = (bid & 7) * q + (bid >> 3);
    const int m0 = (bid % gm) * 128;
    const int n0 = (bid / gm) * 128;

    const int kbeg = blockIdx.y * kchunk;
    const int kend = (kbeg + kchunk < Kd) ? (kbeg + kchunk) : Kd;

    const int w = tid >> 6, l = tid & 63;
    const int wm = w & 1, wn = w >> 1;
    const int lr = l & 15, lg = l >> 4;

    const int ar = tid >> 1, ah = tid & 1;
    const int aw0 = (ar >> 4) * 512 + (((ah * 2) * 16 + (ar & 15)) * 8);
    const int aw1 = aw0 + 128;

    const int KP = Kd >> 5;
    const int np0 = n0 >> 4;

    f32x4 acc[4][4];
#pragma unroll
    for (int a = 0; a < 4; ++a)
#pragma unroll
        for (int b = 0; b < 4; ++b) acc[a][b] = (f32x4){0.f, 0.f, 0.f, 0.f};

    float xf[16];
    f16x8 sah[2], sal[2];

    auto issueA = [&](int k0) {
        if (AK == 0) {
            const float* Ap = (const float*)Av + (size_t)(m0 + ar) * lda + k0 + ah * 16;
            *(float4*)&xf[0]  = *(const float4*)(Ap + 0);
            *(float4*)&xf[4]  = *(const float4*)(Ap + 4);
            *(float4*)&xf[8]  = *(const float4*)(Ap + 8);
            *(float4*)&xf[12] = *(const float4*)(Ap + 12);
        } else if (AK == 3) {
            const _Float16* Ap = (const _Float16*)Av + (size_t)(m0 + ar) * lda + k0 + ah * 16;
            sah[0] = *(const f16x8*)(Ap + 0);
            sah[1] = *(const f16x8*)(Ap + 8);
        }
    };
    auto cvtA = [&]() {
        if (AK == 0) {
#pragma unroll
            for (int c2 = 0; c2 < 2; ++c2)
#pragma unroll
                for (int j = 0; j < 8; ++j) {
                    const float xv = xf[c2 * 8 + j];
                    const _Float16 h = (_Float16)xv;
                    sah[c2][j] = h;
                    if (ASPLIT) sal[c2][j] = (_Float16)(xv - (float)h);
                }
        }
    };
    auto writeA = [&](int p) {
        *(f16x8*)&Sh[p][S_AH][aw0] = sah[0];
        *(f16x8*)&Sh[p][S_AH][aw1] = sah[1];
        if (ASPLIT) {
            *(f16x8*)&Sh[p][S_AL][aw0] = sal[0];
            *(f16x8*)&Sh[p][S_AL][aw1] = sal[1];
        }
    };
    auto stageGL = [&](int k0, int p) {
        const int kp = k0 >> 5;
#pragma unroll
        for (int qq = 0; qq < 2; ++qq) {
            const int st = 2 * w + qq;
            const size_t go = ((size_t)(np0 + st) * KP + kp) * 512 + (size_t)l * 8;
            gl_lds(Bph + go, &Sh[p][S_BH][st * 512], l);
            if (BSPLIT) gl_lds(Bpl + go, &Sh[p][S_BL][st * 512], l);
        }
    };
    auto domfma = [&](int b) {
        f16x8 fah[4], fal[4], fbh[4], fbl[4];
#pragma unroll
        for (int t = 0; t < 4; ++t) {
            fah[t] = *(const f16x8*)&Sh[b][S_AH][(wm * 4 + t) * 512 + l * 8];
            if (ASPLIT) fal[t] = *(const f16x8*)&Sh[b][S_AL][(wm * 4 + t) * 512 + l * 8];
            fbh[t] = *(const f16x8*)&Sh[b][S_BH][(wn * 4 + t) * 512 + l * 8];
            if (BSPLIT) fbl[t] = *(const f16x8*)&Sh[b][S_BL][(wn * 4 + t) * 512 + l * 8];
        }
        __builtin_amdgcn_s_setprio(1);
#pragma unroll
        for (int mt = 0; mt < 4; ++mt)
#pragma unroll
            for (int nt = 0; nt < 4; ++nt) {
                f32x4& a = acc[mt][nt];
                a = __builtin_amdgcn_mfma_f32_16x16x32_f16(fah[mt], fbh[nt], a, 0, 0, 0);
                if (BSPLIT)
                    a = __builtin_amdgcn_mfma_f32_16x16x32_f16(fah[mt], fbl[nt], a, 0, 0, 0);
                if (ASPLIT)
                    a = __builtin_amdgcn_mfma_f32_16x16x32_f16(fal[mt], fbh[nt], a, 0, 0, 0);
            }
        __builtin_amdgcn_s_setprio(0);
    };

    issueA(kbeg); cvtA(); writeA(0);
    stageGL(kbeg, 0);
    __syncthreads();
    int p = 0;
    for (int k0 = kbeg; k0 < kend; k0 += 32) {
        const bool more = (k0 + 32 < kend);
        if (more) {
            issueA(k0 + 32);
            stageGL(k0 + 32, p ^ 1);
        }
        domfma(p);
        if (more) { cvtA(); writeA(p ^ 1); }
        __syncthreads();
        p ^= 1;
    }

#pragma unroll
    for (int mt = 0; mt < 4; ++mt) {
        const int row = m0 + wm * 64 + mt * 16 + lg * 4;
#pragma unroll
        for (int nt = 0; nt < 4; ++nt) {
            const int col = n0 + wn * 64 + nt * 16 + lr;
            if (Ncap == 0 || col < Ncap) {
#pragma unroll
                for (int j = 0; j < 4; ++j) {
                    float v = acc[mt][nt][j];
                    if (EPI == 1) {
                        v += bias[col];
                        v = (v > 20.f) ? v : __logf(1.f + __expf(v));
                    }
                    const size_t off = (size_t)(row + j) * ldc + col;
                    if (ATOMIC)      atomicAdd(&((float*)Cv)[off], v);
                    else if (OUTF16) ((_Float16*)Cv)[off] = (_Float16)v;
                    else             ((float*)Cv)[off] = v;
                }
            }
        }
    }
}

// ---------------------------------------------------------------------------
// Pack W [Kd][Nd] fp32 -> f16 B-panels [Nd/16][Kd/32][512]; lo only if Pl.
// ---------------------------------------------------------------------------
__global__ __launch_bounds__(128) void pack_bp(
    const float* __restrict__ W, _Float16* __restrict__ Ph,
    _Float16* __restrict__ Pl, int Kd, int Nd)
{
    __shared__ float t[32][33];
    const int tid = threadIdx.x;
    const int n0 = blockIdx.x * 32, k0 = blockIdx.y * 32;
#pragma unroll
    for (int h = 0; h < 2; ++h) {
        const int qd = tid + h * 128;
        const int kk = qd >> 3, qq = qd & 7;
        *(float4*)&t[kk][qq * 4] = *(const float4*)(W + (size_t)(k0 + kk) * Nd + n0 + qq * 4);
    }
    __syncthreads();
    const int c = tid >> 5, nn = tid & 31;
    const int np = (n0 + nn) >> 4;
    const int r  = nn & 15;
    const int kp = k0 >> 5;
    const size_t base = ((size_t)np * (Kd >> 5) + kp) * 512 + (c * 16 + r) * 8;
    f16x8 vh, vl;
#pragma unroll
    for (int j = 0; j < 8; ++j) {
        const float v = t[c * 8 + j][nn];
        const _Float16 h = (_Float16)v;
        vh[j] = h;
        vl[j] = (_Float16)(v - (float)h);
    }
    *(f16x8*)&Ph[base] = vh;
    if (Pl) *(f16x8*)&Pl[base] = vl;
}

// ---------------------------------------------------------------------------
// Pack A fp32 [M][K] row-major -> hi f16 A-panels [M/16][K/32][512].
// ---------------------------------------------------------------------------
__global__ __launch_bounds__(256) void pack_ap(
    const float* __restrict__ A, int lda,
    _Float16* __restrict__ Ph, int Kd)
{
    const int tid = threadIdx.x;
    const int mp = blockIdx.x;
    const int r = tid >> 4, c8 = tid & 15;
    const int k0 = blockIdx.y * 128 + c8 * 8;
    const float* Ap = A + (size_t)(mp * 16 + r) * lda + k0;
    const float4 v0 = *(const float4*)Ap;
    const float4 v1 = *(const float4*)(Ap + 4);
    const float x[8] = {v0.x, v0.y, v0.z, v0.w, v1.x, v1.y, v1.z, v1.w};
    f16x8 vh;
#pragma unroll
    for (int j = 0; j < 8; ++j) vh[j] = (_Float16)x[j];
    const int kp = k0 >> 5;
    const int c  = (k0 >> 3) & 3;
    const size_t base = ((size_t)mp * (Kd >> 5) + kp) * 512 + (c * 16 + r) * 8;
    *(f16x8*)&Ph[base] = vh;
}

// ---------------------------------------------------------------------------
// Causal depthwise conv (K=4) + bias + silu (4ch x 8t / thread); zeroes ssm.
// proj (x-half) f16 ld 2I; xconv written f16. Tail saved f32.
// ---------------------------------------------------------------------------
__global__ __launch_bounds__(256) void conv_silu_kernel(
    const _Float16* __restrict__ proj,
    const float* __restrict__ xtail_in,
    float* __restrict__ xtail_out,
    const float* __restrict__ w,
    const float* __restrict__ b,
    _Float16* __restrict__ xconv,
    float* __restrict__ ssm,
    int first)
{
    const int gid = blockIdx.x * 256 + threadIdx.x;
    if (gid < (LC * 160) / 4)
        *(float4*)(ssm + (size_t)gid * 4) = make_float4(0.f, 0.f, 0.f, 0.f);

    const int i4 = gid & (I_DIM / 4 - 1);
    const int t8 = gid >> 10;
    const int i = i4 * 4;
    const int tt0 = t8 * 8;

    const float4 w0 = *(const float4*)(w + (size_t)(i + 0) * 4);
    const float4 w1 = *(const float4*)(w + (size_t)(i + 1) * 4);
    const float4 w2 = *(const float4*)(w + (size_t)(i + 2) * 4);
    const float4 w3 = *(const float4*)(w + (size_t)(i + 3) * 4);
    const float4 bb = *(const float4*)(b + i);

    auto ldrow = [&](int row) -> float4 {
        const f16x4v v = *(const f16x4v*)(proj + (size_t)row * (2 * I_DIM) + i);
        return make_float4((float)v[0], (float)v[1], (float)v[2], (float)v[3]);
    };

    float4 r[11];
    if (tt0 >= 3) {
#pragma unroll
        for (int s = 0; s < 11; ++s) r[s] = ldrow(tt0 - 3 + s);
    } else {
#pragma unroll
        for (int s = 0; s < 3; ++s)
            r[s] = first ? make_float4(0.f, 0.f, 0.f, 0.f)
                         : *(const float4*)(xtail_in + (size_t)s * I_DIM + i);
#pragma unroll
        for (int s = 3; s < 11; ++s) r[s] = ldrow(tt0 - 3 + s);
    }

#pragma unroll
    for (int s = 0; s < 8; ++s) {
        float4 y = bb;
        y.x = fmaf(w0.x, r[s].x, y.x); y.x = fmaf(w0.y, r[s+1].x, y.x);
        y.x = fmaf(w0.z, r[s+2].x, y.x); y.x = fmaf(w0.w, r[s+3].x, y.x);
        y.y = fmaf(w1.x, r[s].y, y.y); y.y = fmaf(w1.y, r[s+1].y, y.y);
        y.y = fmaf(w1.z, r[s+2].y, y.y); y.y = fmaf(w1.w, r[s+3].y, y.y);
        y.z = fmaf(w2.x, r[s].z, y.z); y.z = fmaf(w2.y, r[s+1].z, y.z);
        y.z = fmaf(w2.z, r[s+2].z, y.z); y.z = fmaf(w2.w, r[s+3].z, y.z);
        y.w = fmaf(w3.x, r[s].w, y.w); y.w = fmaf(w3.y, r[s+1].w, y.w);
        y.w = fmaf(w3.z, r[s+2].w, y.w); y.w = fmaf(w3.w, r[s+3].w, y.w);
        y.x = y.x / (1.f + __expf(-y.x));
        y.y = y.y / (1.f + __expf(-y.y));
        y.z = y.z / (1.f + __expf(-y.z));
        y.w = y.w / (1.f + __expf(-y.w));
        f16x4v o;
        o[0] = (_Float16)y.x; o[1] = (_Float16)y.y;
        o[2] = (_Float16)y.z; o[3] = (_Float16)y.w;
        *(f16x4v*)(xconv + (size_t)(tt0 + s) * I_DIM + i) = o;
    }

    if (tt0 == LC - 8) {
#pragma unroll
        for (int qq = 0; qq < 3; ++qq)
            *(float4*)(xtail_out + (size_t)qq * I_DIM + i) = r[8 + qq];
    }
}

// ---------------------------------------------------------------------------
// Segment-parallel scan. delta/gate f16 (ld 2I); u (xc) f16.
// ---------------------------------------------------------------------------
__global__ __launch_bounds__(256) void scan_part1(
    const _Float16* __restrict__ delta,
    const float* __restrict__ ssm,
    const _Float16* __restrict__ xc,
    const float* __restrict__ A_log,
    float* __restrict__ aprod,
    float* __restrict__ hend)
{
    __shared__ float Bs[TSEG][16];
    const int tid = threadIdx.x;
    const int i = blockIdx.x * 128 + (tid >> 1);
    const int half = tid & 1;
    const int seg = blockIdx.y;
    const int t0 = seg * TSEG;

    {
        const int tt = tid >> 2, c = (tid & 3) * 4;
        *(float4*)&Bs[tt][c] = *(const float4*)&ssm[(size_t)(t0 + tt) * 160 + 128 + c];
    }
    __syncthreads();

    float Ai[8], h[8], ap[8];
    {
        const float4 a0 = *(const float4*)&A_log[(size_t)i * 16 + half * 8];
        const float4 a1 = *(const float4*)&A_log[(size_t)i * 16 + half * 8 + 4];
        const float al[8] = {a0.x, a0.y, a0.z, a0.w, a1.x, a1.y, a1.z, a1.w};
#pragma unroll
        for (int n = 0; n < 8; ++n) { Ai[n] = -expf(al[n]); h[n] = 0.f; ap[n] = 1.f; }
    }

    float d0 = (float)delta[(size_t)t0 * (2 * I_DIM) + i];
    float u0 = (float)xc[(size_t)t0 * I_DIM + i];
    float d1 = (float)delta[(size_t)(t0 + 1) * (2 * I_DIM) + i];
    float u1 = (float)xc[(size_t)(t0 + 1) * I_DIM + i];
    for (int t = 0; t < TSEG; t += 2) {
        float d2 = 0.f, u2 = 0.f, d3 = 0.f, u3 = 0.f;
        if (t + 3 < TSEG) {
            d2 = (float)delta[(size_t)(t0 + t + 2) * (2 * I_DIM) + i];
            u2 = (float)xc[(size_t)(t0 + t + 2) * I_DIM + i];
            d3 = (float)delta[(size_t)(t0 + t + 3) * (2 * I_DIM) + i];
            u3 = (float)xc[(size_t)(t0 + t + 3) * I_DIM + i];
        }
        {
            const float du = d0 * u0;
#pragma unroll
            for (int n = 0; n < 8; ++n) {
                const float a = __expf(d0 * Ai[n]);
                h[n] = fmaf(h[n], a, du * Bs[t][half * 8 + n]);
                ap[n] *= a;
            }
        }
        {
            const float du = d1 * u1;
#pragma unroll
            for (int n = 0; n < 8; ++n) {
                const float a = __expf(d1 * Ai[n]);
                h[n] = fmaf(h[n], a, du * Bs[t + 1][half * 8 + n]);
                ap[n] *= a;
            }
        }
        d0 = d2; u0 = u2; d1 = d3; u1 = u3;
    }

    const size_t base = (size_t)seg * IN_DIM + (size_t)i * 16 + half * 8;
#pragma unroll
    for (int qq = 0; qq < 2; ++qq) {
        float4 va = {ap[qq * 4 + 0], ap[qq * 4 + 1], ap[qq * 4 + 2], ap[qq * 4 + 3]};
        float4 vh = {h[qq * 4 + 0], h[qq * 4 + 1], h[qq * 4 + 2], h[qq * 4 + 3]};
        *(float4*)&aprod[base + qq * 4] = va;
        *(float4*)&hend[base + qq * 4]  = vh;
    }
}

__global__ __launch_bounds__(256) void scan_part2(
    const float* __restrict__ aprod,
    float* __restrict__ hend,
    float* __restrict__ hstate,
    int first)
{
    const int gid = blockIdx.x * 256 + threadIdx.x;
    float h = first ? 0.f : hstate[gid];
    for (int s = 0; s < SEG; ++s) {
        const size_t idx = (size_t)s * IN_DIM + gid;
        const float ap = aprod[idx];
        const float he = hend[idx];
        hend[idx] = h;
        h = fmaf(ap, h, he);
    }
    hstate[gid] = h;
}

// Phase 3: re-run segment from h_start; z (f16) written in GEMM4 A-panel layout.
__global__ __launch_bounds__(256) void scan_part3(
    const _Float16* __restrict__ delta,
    const _Float16* __restrict__ gate,
    const float* __restrict__ ssm,
    const _Float16* __restrict__ xc,
    _Float16* __restrict__ zPh,
    const float* __restrict__ A_log,
    const float* __restrict__ Dp,
    const float* __restrict__ hstart)  // [SEG][I][N]
{
    __shared__ float BCs[TSEG][32];
    const int tid = threadIdx.x;
    const int i = blockIdx.x * 128 + (tid >> 1);
    const int half = tid & 1;
    const int seg = blockIdx.y;
    const int t0 = seg * TSEG;

    {
        const int tt = tid >> 2, c = (tid & 3) * 8;
        *(float4*)&BCs[tt][c]     = *(const float4*)&ssm[(size_t)(t0 + tt) * 160 + 128 + c];
        *(float4*)&BCs[tt][c + 4] = *(const float4*)&ssm[(size_t)(t0 + tt) * 160 + 132 + c];
    }
    __syncthreads();

    float Ai[8], h[8];
    {
        const float4 a0 = *(const float4*)&A_log[(size_t)i * 16 + half * 8];
        const float4 a1 = *(const float4*)&A_log[(size_t)i * 16 + half * 8 + 4];
        const float al[8] = {a0.x, a0.y, a0.z, a0.w, a1.x, a1.y, a1.z, a1.w};
#pragma unroll
        for (int n = 0; n < 8; ++n) Ai[n] = -expf(al[n]);
        const size_t base = (size_t)seg * IN_DIM + (size_t)i * 16 + half * 8;
        const float4 h0 = *(const float4*)&hstart[base];
        const float4 h1 = *(const float4*)&hstart[base + 4];
        h[0] = h0.x; h[1] = h0.y; h[2] = h0.z; h[3] = h0.w;
        h[4] = h1.x; h[5] = h1.y; h[6] = h1.z; h[7] = h1.w;
    }
    const float Di = Dp[i];

    const int kp = i >> 5, cc = (i >> 3) & 3, jj = i & 7;
    const size_t zb = (size_t)kp * 512 + (size_t)cc * 128 + jj;

    float d0 = (float)delta[(size_t)t0 * (2 * I_DIM) + i];
    float u0 = (float)xc[(size_t)t0 * I_DIM + i];
    float g0 = (float)gate[(size_t)t0 * (2 * I_DIM) + i];
    float d1 = (float)delta[(size_t)(t0 + 1) * (2 * I_DIM) + i];
    float u1 = (float)xc[(size_t)(t0 + 1) * I_DIM + i];
    float g1 = (float)gate[(size_t)(t0 + 1) * (2 * I_DIM) + i];
    for (int t = 0; t < TSEG; t += 2) {
        float d2 = 0.f, u2 = 0.f, g2 = 0.f, d3 = 0.f, u3 = 0.f, g3 = 0.f;
        if (t + 3 < TSEG) {
            d2 = (float)delta[(size_t)(t0 + t + 2) * (2 * I_DIM) + i];
            u2 = (float)xc[(size_t)(t0 + t + 2) * I_DIM + i];
            g2 = (float)gate[(size_t)(t0 + t + 2) * (2 * I_DIM) + i];
            d3 = (float)delta[(size_t)(t0 + t + 3) * (2 * I_DIM) + i];
            u3 = (float)xc[(size_t)(t0 + t + 3) * I_DIM + i];
            g3 = (float)gate[(size_t)(t0 + t + 3) * (2 * I_DIM) + i];
        }
#pragma unroll
        for (int ss = 0; ss < 2; ++ss) {
            const float d = ss ? d1 : d0;
            const float u = ss ? u1 : u0;
            const float g = ss ? g1 : g0;
            const int tt = t + ss;
            const float du = d * u;
            float y = 0.f;
#pragma unroll
            for (int n = 0; n < 8; ++n) {
                const float a = __expf(d * Ai[n]);
                h[n] = fmaf(h[n], a, du * BCs[tt][half * 8 + n]);
                y = fmaf(h[n], BCs[tt][16 + half * 8 + n], y);
            }
            y += __shfl_xor(y, 1);
            if (half == 0) {
                const float sg = g / (1.f + __expf(-g));
                const float zv = (y + u * Di) * sg;
                const int row = t0 + tt;
                zPh[((size_t)(row >> 4) * (I_DIM >> 5)) * 512 + zb + (size_t)(row & 15) * 8]
                    = (_Float16)zv;
            }
        }
        d0 = d2; u0 = u2; g0 = g2; d1 = d3; u1 = u3; g1 = g3;
    }
}

// ---------------------------------------------------------------------------
extern "C" void kernel_launch(void* const* d_in, const int* in_sizes, int n_in,
                              void* d_out, int out_size, void* d_ws, size_t ws_size,
                              hipStream_t stream)
{
    const float* hs      = (const float*)d_in[0];
    const float* W_in    = (const float*)d_in[1];
    const float* conv_w  = (const float*)d_in[2];
    const float* conv_b  = (const float*)d_in[3];
    const float* W_x     = (const float*)d_in[4];
    const float* W_dt    = (const float*)d_in[5];
    const float* dt_bias = (const float*)d_in[6];
    const float* A_log   = (const float*)d_in[7];
    const float* Dp      = (const float*)d_in[8];
    const float* W_out   = (const float*)d_in[9];
    float* out = (float*)d_out;

    // workspace layout (~223 MB)
    char* p = (char*)d_ws;
    auto alloc = [&](size_t bytes) {
        char* r = p;
        p += (bytes + 255) & ~(size_t)255;
        return r;
    };
    _Float16* proj16 = (_Float16*)alloc((size_t)68 * 1024 * 1024);
    _Float16* xconv16 = (_Float16*)alloc((size_t)LC * I_DIM * 2);  // 32 MB
    float* ssm    = (float*)alloc((size_t)LC * 160 * 4);           // 2.6 MB
    float* xtail  = (float*)alloc((size_t)2 * 3 * I_DIM * 4);
    float* hstate = (float*)alloc((size_t)IN_DIM * 4);
    _Float16* WinPh  = (_Float16*)alloc((size_t)2 * I_DIM * H_DIM * 2);  // 32 MB
    _Float16* WoutPh = (_Float16*)alloc((size_t)H_DIM * I_DIM * 2);      // 16 MB
    _Float16* WdtPh  = (_Float16*)alloc((size_t)I_DIM * R_DIM * 2);
    _Float16* WdtPl  = (_Float16*)alloc((size_t)I_DIM * R_DIM * 2);
    _Float16* WxPh   = (_Float16*)alloc((size_t)256 * I_DIM * 2);
    _Float16* WxPl   = (_Float16*)alloc((size_t)256 * I_DIM * 2);
    _Float16* hsPh   = (_Float16*)alloc((size_t)L_DIM * H_DIM * 2);  // 33.5 MB
    _Float16* zPh    = (_Float16*)alloc((size_t)LC * I_DIM * 2);     // 32 MB

    const dim3 blk(256);
    const int NSSM = R_DIM + 2 * N_DIM;  // 160

    // ---- pack weights + full hs into panel format (once per launch) ----
    pack_bp<<<dim3(2 * I_DIM / 32, H_DIM / 32), dim3(128), 0, stream>>>(
        W_in, WinPh, nullptr, H_DIM, 2 * I_DIM);
    pack_bp<<<dim3(H_DIM / 32, I_DIM / 32), dim3(128), 0, stream>>>(
        W_out, WoutPh, nullptr, I_DIM, H_DIM);
    pack_bp<<<dim3(I_DIM / 32, R_DIM / 32), dim3(128), 0, stream>>>(
        W_dt, WdtPh, WdtPl, R_DIM, I_DIM);
    pack_bp<<<dim3(NSSM / 32, I_DIM / 32), dim3(128), 0, stream>>>(
        W_x, WxPh, WxPl, I_DIM, NSSM);
    pack_ap<<<dim3(L_DIM / 16, H_DIM / 128), blk, 0, stream>>>(
        hs, H_DIM, hsPh, H_DIM);

    for (int c = 0; c < NCHUNK; ++c) {
        const int t0 = c * LC;
        const int first = (c == 0) ? 1 : 0;
        float* out_c = out + (size_t)t0 * H_DIM;
        float* aprod = out_c;                 // scan scratch in out region
        float* hend  = out_c + (size_t)SEG * IN_DIM;  // exact fit: 2*SEG*IN = LC*H
        float* xtA = xtail + (size_t)(c & 1) * 3 * I_DIM;
        float* xtB = xtail + (size_t)((c & 1) ^ 1) * 3 * I_DIM;
        const _Float16* hsPh_c = hsPh + (size_t)(t0 >> 4) * (H_DIM >> 5) * 512;

        // 1) proj(f16) = hs_c @ W_in  (512 blocks)
        gemm_r256<1><<<dim3(512, 1), dim3(512), 0, stream>>>(
            hsPh_c, WinPh, proj16, 2 * I_DIM, H_DIM, LC / 256, H_DIM, 0);

        // 2) xconv(f16) = silu(dwconv(x_pre) + b); zeroes ssm; saves tail
        conv_silu_kernel<<<dim3((LC / 8) * (I_DIM / 4) / 256), blk, 0, stream>>>(
            proj16, xtA, xtB, conv_w, conv_b, xconv16, ssm, first);

        // 3) ssm = xconv @ W_x  (f16 A direct, B split, split-K x8, atomics)
        gemm_p<0, 3, 0, 1, true, 0><<<dim3(2 * (LC / 128), 8), blk, 0, stream>>>(
            xconv16, I_DIM, nullptr, WxPh, WxPl, ssm, NSSM,
            I_DIM, NSSM, LC / 128, I_DIM / 8, nullptr);

        // 4) delta(f16) = softplus(ssm[:, :R] @ W_dt + dt_bias) -> proj x-half
        gemm_p<1, 0, 1, 1, false, 1><<<dim3(32 * (LC / 128), 1), blk, 0, stream>>>(
            ssm, NSSM, nullptr, WdtPh, WdtPl, proj16, 2 * I_DIM,
            R_DIM, 0, LC / 128, R_DIM, dt_bias);

        // 5) segment-parallel scan; z -> zPh panels
        scan_part1<<<dim3(I_DIM / 128, SEG), blk, 0, stream>>>(
            proj16, ssm, xconv16, A_log, aprod, hend);
        scan_part2<<<dim3(IN_DIM / 256), blk, 0, stream>>>(
            aprod, hend, hstate, first);
        scan_part3<<<dim3(I_DIM / 128, SEG), blk, 0, stream>>>(
            proj16, proj16 + I_DIM, ssm, xconv16, zPh, A_log, Dp, hend);

        // 6) GEMM4 partials (f16): 4 k-slices of z @ W_out into proj region
        gemm_r256<1><<<dim3((LC / 256) * (H_DIM / 256), 4), dim3(512), 0, stream>>>(
            zPh, WoutPh, proj16, H_DIM, I_DIM, LC / 256,
            I_DIM / 4, (size_t)LC * H_DIM);

        // 7) out_c = P0+P1+P2+P3
        reduce4_f16_kernel<<<dim3(LC * H_DIM / 2048), blk, 0, stream>>>(
            proj16, out_c);
    }
}

// Round 21
// 987.541 us; speedup vs baseline: 5.7363x; 1.0241x over previous
//
#include <hip/hip_runtime.h>
#include <cmath>
#include <stdint.h>

#define H_DIM 2048
#define I_DIM 4096
#define N_DIM 16
#define R_DIM 128
#define K_CONV 4
#define L_DIM 8192
#define LC 4096                 // chunk length
#define NCHUNK (L_DIM / LC)
#define SEG 64                  // scan segments per chunk
#define TSEG (LC / SEG)         // 64 steps per segment
#define IN_DIM (I_DIM * N_DIM)  // 65536 recurrences

typedef _Float16 f16x8 __attribute__((ext_vector_type(8)));
typedef _Float16 f16x4v __attribute__((ext_vector_type(4)));
typedef float    f32x4 __attribute__((ext_vector_type(4)));

// direct HBM->LDS, 16B per lane; LDS base must be wave-uniform (HW adds lane*16)
__device__ __forceinline__ void gl_lds(const _Float16* g, _Float16* lbase, int lane) {
#if __has_builtin(__builtin_amdgcn_global_load_lds)
    __builtin_amdgcn_global_load_lds(
        (const __attribute__((address_space(1))) void*)g,
        (__attribute__((address_space(3))) void*)lbase, 16, 0, 0);
#else
    *(f16x8*)&lbase[lane * 8] = *(const f16x8*)g;
#endif
}

// ---------------------------------------------------------------------------
// 256x256 panel GEMM (GEMM1 & GEMM4): A direct global->VGPR (panel layout is
// fragment-ordered), B staged in LDS via 3-buffer counted-vmcnt gl_lds.
// 512 threads = 8 waves (4m x 2n), wave tile 64x128, acc[4][8]. BK=32.
// LDS = 48KB. launch_bounds(512,2): acc[4][8] needs >=160 VGPR, so 1 block/CU
// is the max; (512,4) forces 64 VGPR and spills the accumulator (round-19:
// 8.6 GB scratch traffic/dispatch, 5.6ms total). Do NOT raise this.
// Steady wait: B(k+1)2 + B(k+2)2 + A(k+1)4 in flight -> vmcnt(8).
// Split-K via blockIdx.y*kchunk, partials at C + y*partStride. OUTF16 store.
// Requires KT = kchunk/32 even and >= 4.
// ---------------------------------------------------------------------------
template <int OUTF16>
__global__ __launch_bounds__(512, 2) void gemm_r256(
    const _Float16* __restrict__ Aph,
    const _Float16* __restrict__ Bph,
    void* __restrict__ Cv, int ldc, int Kd, int gm,
    int kchunk, size_t partStride)
{
    __shared__ __align__(16) _Float16 Bs[3][8192];  // [buf][16 n-panels]

    const int tid = threadIdx.x;
    int bid = blockIdx.x;
    const int q = gridDim.x >> 3;
    bid = (bid & 7) * q + (bid >> 3);    // bijective XCD swizzle (grid % 8 == 0)
    const int m0 = (bid % gm) * 256;
    const int n0 = (bid / gm) * 256;
    const int kbeg = blockIdx.y * kchunk;

    const int w = tid >> 6, l = tid & 63;
    const int wm = w & 3, wn = w >> 2;   // 4m x 2n waves
    const int lr = l & 15, lg = l >> 4;

    const int KP = Kd >> 5;
    const int np0 = n0 >> 4, mp0 = m0 >> 4;

    f32x4 acc[4][8];
#pragma unroll
    for (int a = 0; a < 4; ++a)
#pragma unroll
        for (int b = 0; b < 8; ++b) acc[a][b] = (f32x4){0.f, 0.f, 0.f, 0.f};

    // wave's 4 A row-panels: mp0 + wm*4 + t
    const _Float16* Abase = Aph + ((size_t)(mp0 + wm * 4) * KP) * 512 + (size_t)l * 8;
    const size_t Astride = (size_t)KP * 512;

    f16x8 faA[4], faB[4];

    auto loadA = [&](int k0, f16x8* fa) {
        const size_t ko = (size_t)(k0 >> 5) * 512;
#pragma unroll
        for (int t = 0; t < 4; ++t)
            fa[t] = *(const f16x8*)(Abase + (size_t)t * Astride + ko);
    };
    auto stageB = [&](int k0, int p) {   // 2 gl_lds / thread
        const int kp = k0 >> 5;
#pragma unroll
        for (int s = 0; s < 2; ++s) {
            const int st = w + s * 8;
            gl_lds(Bph + ((size_t)(np0 + st) * KP + kp) * 512 + (size_t)l * 8,
                   &Bs[p][st * 512], l);
        }
    };
    auto domfma = [&](int p, f16x8* fa) {
        f16x8 fb[8];
#pragma unroll
        for (int nt = 0; nt < 8; ++nt)
            fb[nt] = *(const f16x8*)&Bs[p][(wn * 8 + nt) * 512 + l * 8];
        __builtin_amdgcn_s_setprio(1);
#pragma unroll
        for (int mt = 0; mt < 4; ++mt)
#pragma unroll
            for (int nt = 0; nt < 8; ++nt)
                acc[mt][nt] = __builtin_amdgcn_mfma_f32_16x16x32_f16(
                    fa[mt], fb[nt], acc[mt][nt], 0, 0, 0);
        __builtin_amdgcn_s_setprio(0);
    };

    const int KT = kchunk >> 5;          // even, >= 4
    stageB(kbeg, 0);
    stageB(kbeg + 32, 1);
    loadA(kbeg, faA);

    int k = 0;
    for (; k + 3 < KT; k += 2) {
        stageB(kbeg + (k + 2) * 32, (k + 2) % 3);
        loadA(kbeg + (k + 1) * 32, faB);
        asm volatile("s_waitcnt vmcnt(8)" ::: "memory");
        __builtin_amdgcn_s_barrier();
        __builtin_amdgcn_sched_barrier(0);
        domfma(k % 3, faA);
        __builtin_amdgcn_s_barrier();

        stageB(kbeg + (k + 3) * 32, (k + 3) % 3);
        loadA(kbeg + (k + 2) * 32, faA);
        asm volatile("s_waitcnt vmcnt(8)" ::: "memory");
        __builtin_amdgcn_s_barrier();
        __builtin_amdgcn_sched_barrier(0);
        domfma((k + 1) % 3, faB);
        __builtin_amdgcn_s_barrier();
    }
    // k == KT-2
    loadA(kbeg + (KT - 1) * 32, faB);
    asm volatile("s_waitcnt vmcnt(4)" ::: "memory");
    __builtin_amdgcn_s_barrier();
    __builtin_amdgcn_sched_barrier(0);
    domfma((KT - 2) % 3, faA);
    __builtin_amdgcn_s_barrier();
    asm volatile("s_waitcnt vmcnt(0)" ::: "memory");
    __builtin_amdgcn_s_barrier();
    __builtin_amdgcn_sched_barrier(0);
    domfma((KT - 1) % 3, faB);

#pragma unroll
    for (int mt = 0; mt < 4; ++mt) {
        const int row = m0 + wm * 64 + mt * 16 + lg * 4;
#pragma unroll
        for (int nt = 0; nt < 8; ++nt) {
            const int col = n0 + wn * 128 + nt * 16 + lr;
#pragma unroll
            for (int j = 0; j < 4; ++j) {
                if (OUTF16) {
                    _Float16* C = (_Float16*)Cv + (size_t)blockIdx.y * partStride;
                    C[(size_t)(row + j) * ldc + col] = (_Float16)acc[mt][nt][j];
                } else {
                    float* C = (float*)Cv + (size_t)blockIdx.y * partStride;
                    C[(size_t)(row + j) * ldc + col] = acc[mt][nt][j];
                }
            }
        }
    }
}

// ---------------------------------------------------------------------------
// out = P0+P1 (f16 partials, f32 out), 8 elems / thread.
// ---------------------------------------------------------------------------
__global__ __launch_bounds__(256) void reduce2_f16_kernel(
    const _Float16* __restrict__ P, float* __restrict__ out)
{
    const size_t idx = ((size_t)blockIdx.x * 256 + threadIdx.x) * 8;
    const size_t S = (size_t)LC * H_DIM;
    const f16x8 a = *(const f16x8*)(P + idx);
    const f16x8 b = *(const f16x8*)(P + S + idx);
    float r[8];
#pragma unroll
    for (int j = 0; j < 8; ++j)
        r[j] = (float)a[j] + (float)b[j];
    *(float4*)(out + idx)     = *(float4*)&r[0];
    *(float4*)(out + idx + 4) = *(float4*)&r[4];
}

// ---------------------------------------------------------------------------
// 128x128 panel GEMM (GEMM2/3), 2-buffer schedule.
// AK=0: fp32 A reg-split. AK=3: f16 A rows, hi-only, no cvt (xconv path).
// ASPLIT/BSPLIT lo-correction; OUTF16: store f16 (non-atomic only).
// ---------------------------------------------------------------------------
template <int EPI, int AK, int ASPLIT, int BSPLIT, bool ATOMIC, int OUTF16>
__global__ __launch_bounds__(256, ASPLIT ? 2 : (BSPLIT ? 3 : 4)) void gemm_p(
    const void* __restrict__ Av, int lda,
    const _Float16* __restrict__ Aph,
    const _Float16* __restrict__ Bph, const _Float16* __restrict__ Bpl,
    void* __restrict__ Cv, int ldc,
    int Kd, int Ncap, int gm, int kchunk,
    const float* __restrict__ bias)
{
    constexpr int S_AH = 0;
    constexpr int S_AL = ASPLIT ? 1 : 0;
    constexpr int S_BH = ASPLIT ? 2 : 1;
    constexpr int S_BL = S_BH + 1;
    constexpr int NSLOT = S_BH + 1 + BSPLIT;
    __shared__ __align__(16) _Float16 Sh[2][NSLOT][4096];

    const int tid = threadIdx.x;
    int bid = blockIdx.x;
    const int q = gridDim.x >> 3;
    bid = (bid & 7) * q + (bid >> 3);
    const int m0 = (bid % gm) * 128;
    const int n0 = (bid / gm) * 128;

    const int kbeg = blockIdx.y * kchunk;
    const int kend = (kbeg + kchunk < Kd) ? (kbeg + kchunk) : Kd;

    const int w = tid >> 6, l = tid & 63;
    const int wm = w & 1, wn = w >> 1;
    const int lr = l & 15, lg = l >> 4;

    const int ar = tid >> 1, ah = tid & 1;
    const int aw0 = (ar >> 4) * 512 + (((ah * 2) * 16 + (ar & 15)) * 8);
    const int aw1 = aw0 + 128;

    const int KP = Kd >> 5;
    const int np0 = n0 >> 4;

    f32x4 acc[4][4];
#pragma unroll
    for (int a = 0; a < 4; ++a)
#pragma unroll
        for (int b = 0; b < 4; ++b) acc[a][b] = (f32x4){0.f, 0.f, 0.f, 0.f};

    float xf[16];
    f16x8 sah[2], sal[2];

    auto issueA = [&](int k0) {
        if (AK == 0) {
            const float* Ap = (const float*)Av + (size_t)(m0 + ar) * lda + k0 + ah * 16;
            *(float4*)&xf[0]  = *(const float4*)(Ap + 0);
            *(float4*)&xf[4]  = *(const float4*)(Ap + 4);
            *(float4*)&xf[8]  = *(const float4*)(Ap + 8);
            *(float4*)&xf[12] = *(const float4*)(Ap + 12);
        } else if (AK == 3) {
            const _Float16* Ap = (const _Float16*)Av + (size_t)(m0 + ar) * lda + k0 + ah * 16;
            sah[0] = *(const f16x8*)(Ap + 0);
            sah[1] = *(const f16x8*)(Ap + 8);
        }
    };
    auto cvtA = [&]() {
        if (AK == 0) {
#pragma unroll
            for (int c2 = 0; c2 < 2; ++c2)
#pragma unroll
                for (int j = 0; j < 8; ++j) {
                    const float xv = xf[c2 * 8 + j];
                    const _Float16 h = (_Float16)xv;
                    sah[c2][j] = h;
                    if (ASPLIT) sal[c2][j] = (_Float16)(xv - (float)h);
                }
        }
    };
    auto writeA = [&](int p) {
        *(f16x8*)&Sh[p][S_AH][aw0] = sah[0];
        *(f16x8*)&Sh[p][S_AH][aw1] = sah[1];
        if (ASPLIT) {
            *(f16x8*)&Sh[p][S_AL][aw0] = sal[0];
            *(f16x8*)&Sh[p][S_AL][aw1] = sal[1];
        }
    };
    auto stageGL = [&](int k0, int p) {
        const int kp = k0 >> 5;
#pragma unroll
        for (int qq = 0; qq < 2; ++qq) {
            const int st = 2 * w + qq;
            const size_t go = ((size_t)(np0 + st) * KP + kp) * 512 + (size_t)l * 8;
            gl_lds(Bph + go, &Sh[p][S_BH][st * 512], l);
            if (BSPLIT) gl_lds(Bpl + go, &Sh[p][S_BL][st * 512], l);
        }
    };
    auto domfma = [&](int b) {
        f16x8 fah[4], fal[4], fbh[4], fbl[4];
#pragma unroll
        for (int t = 0; t < 4; ++t) {
            fah[t] = *(const f16x8*)&Sh[b][S_AH][(wm * 4 + t) * 512 + l * 8];
            if (ASPLIT) fal[t] = *(const f16x8*)&Sh[b][S_AL][(wm * 4 + t) * 512 + l * 8];
            fbh[t] = *(const f16x8*)&Sh[b][S_BH][(wn * 4 + t) * 512 + l * 8];
            if (BSPLIT) fbl[t] = *(const f16x8*)&Sh[b][S_BL][(wn * 4 + t) * 512 + l * 8];
        }
        __builtin_amdgcn_s_setprio(1);
#pragma unroll
        for (int mt = 0; mt < 4; ++mt)
#pragma unroll
            for (int nt = 0; nt < 4; ++nt) {
                f32x4& a = acc[mt][nt];
                a = __builtin_amdgcn_mfma_f32_16x16x32_f16(fah[mt], fbh[nt], a, 0, 0, 0);
                if (BSPLIT)
                    a = __builtin_amdgcn_mfma_f32_16x16x32_f16(fah[mt], fbl[nt], a, 0, 0, 0);
                if (ASPLIT)
                    a = __builtin_amdgcn_mfma_f32_16x16x32_f16(fal[mt], fbh[nt], a, 0, 0, 0);
            }
        __builtin_amdgcn_s_setprio(0);
    };

    issueA(kbeg); cvtA(); writeA(0);
    stageGL(kbeg, 0);
    __syncthreads();
    int p = 0;
    for (int k0 = kbeg; k0 < kend; k0 += 32) {
        const bool more = (k0 + 32 < kend);
        if (more) {
            issueA(k0 + 32);
            stageGL(k0 + 32, p ^ 1);
        }
        domfma(p);
        if (more) { cvtA(); writeA(p ^ 1); }
        __syncthreads();
        p ^= 1;
    }

#pragma unroll
    for (int mt = 0; mt < 4; ++mt) {
        const int row = m0 + wm * 64 + mt * 16 + lg * 4;
#pragma unroll
        for (int nt = 0; nt < 4; ++nt) {
            const int col = n0 + wn * 64 + nt * 16 + lr;
            if (Ncap == 0 || col < Ncap) {
#pragma unroll
                for (int j = 0; j < 4; ++j) {
                    float v = acc[mt][nt][j];
                    if (EPI == 1) {
                        v += bias[col];
                        v = (v > 20.f) ? v : __logf(1.f + __expf(v));
                    }
                    const size_t off = (size_t)(row + j) * ldc + col;
                    if (ATOMIC)      atomicAdd(&((float*)Cv)[off], v);
                    else if (OUTF16) ((_Float16*)Cv)[off] = (_Float16)v;
                    else             ((float*)Cv)[off] = v;
                }
            }
        }
    }
}

// ---------------------------------------------------------------------------
// Pack W [Kd][Nd] fp32 -> f16 B-panels [Nd/16][Kd/32][512]; lo only if Pl.
// ---------------------------------------------------------------------------
__global__ __launch_bounds__(128) void pack_bp(
    const float* __restrict__ W, _Float16* __restrict__ Ph,
    _Float16* __restrict__ Pl, int Kd, int Nd)
{
    __shared__ float t[32][33];
    const int tid = threadIdx.x;
    const int n0 = blockIdx.x * 32, k0 = blockIdx.y * 32;
#pragma unroll
    for (int h = 0; h < 2; ++h) {
        const int qd = tid + h * 128;
        const int kk = qd >> 3, qq = qd & 7;
        *(float4*)&t[kk][qq * 4] = *(const float4*)(W + (size_t)(k0 + kk) * Nd + n0 + qq * 4);
    }
    __syncthreads();
    const int c = tid >> 5, nn = tid & 31;
    const int np = (n0 + nn) >> 4;
    const int r  = nn & 15;
    const int kp = k0 >> 5;
    const size_t base = ((size_t)np * (Kd >> 5) + kp) * 512 + (c * 16 + r) * 8;
    f16x8 vh, vl;
#pragma unroll
    for (int j = 0; j < 8; ++j) {
        const float v = t[c * 8 + j][nn];
        const _Float16 h = (_Float16)v;
        vh[j] = h;
        vl[j] = (_Float16)(v - (float)h);
    }
    *(f16x8*)&Ph[base] = vh;
    if (Pl) *(f16x8*)&Pl[base] = vl;
}

// ---------------------------------------------------------------------------
// Pack A fp32 [M][K] row-major -> hi f16 A-panels [M/16][K/32][512].
// ---------------------------------------------------------------------------
__global__ __launch_bounds__(256) void pack_ap(
    const float* __restrict__ A, int lda,
    _Float16* __restrict__ Ph, int Kd)
{
    const int tid = threadIdx.x;
    const int mp = blockIdx.x;
    const int r = tid >> 4, c8 = tid & 15;
    const int k0 = blockIdx.y * 128 + c8 * 8;
    const float* Ap = A + (size_t)(mp * 16 + r) * lda + k0;
    const float4 v0 = *(const float4*)Ap;
    const float4 v1 = *(const float4*)(Ap + 4);
    const float x[8] = {v0.x, v0.y, v0.z, v0.w, v1.x, v1.y, v1.z, v1.w};
    f16x8 vh;
#pragma unroll
    for (int j = 0; j < 8; ++j) vh[j] = (_Float16)x[j];
    const int kp = k0 >> 5;
    const int c  = (k0 >> 3) & 3;
    const size_t base = ((size_t)mp * (Kd >> 5) + kp) * 512 + (c * 16 + r) * 8;
    *(f16x8*)&Ph[base] = vh;
}

// ---------------------------------------------------------------------------
// Causal depthwise conv (K=4) + bias + silu (4ch x 8t / thread); zeroes ssm.
// proj (x-half) f16 ld 2I; xconv written f16. Tail saved f32.
// ---------------------------------------------------------------------------
__global__ __launch_bounds__(256) void conv_silu_kernel(
    const _Float16* __restrict__ proj,
    const float* __restrict__ xtail_in,
    float* __restrict__ xtail_out,
    const float* __restrict__ w,
    const float* __restrict__ b,
    _Float16* __restrict__ xconv,
    float* __restrict__ ssm,
    int first)
{
    const int gid = blockIdx.x * 256 + threadIdx.x;
    if (gid < (LC * 160) / 4)
        *(float4*)(ssm + (size_t)gid * 4) = make_float4(0.f, 0.f, 0.f, 0.f);

    const int i4 = gid & (I_DIM / 4 - 1);
    const int t8 = gid >> 10;
    const int i = i4 * 4;
    const int tt0 = t8 * 8;

    const float4 w0 = *(const float4*)(w + (size_t)(i + 0) * 4);
    const float4 w1 = *(const float4*)(w + (size_t)(i + 1) * 4);
    const float4 w2 = *(const float4*)(w + (size_t)(i + 2) * 4);
    const float4 w3 = *(const float4*)(w + (size_t)(i + 3) * 4);
    const float4 bb = *(const float4*)(b + i);

    auto ldrow = [&](int row) -> float4 {
        const f16x4v v = *(const f16x4v*)(proj + (size_t)row * (2 * I_DIM) + i);
        return make_float4((float)v[0], (float)v[1], (float)v[2], (float)v[3]);
    };

    float4 r[11];
    if (tt0 >= 3) {
#pragma unroll
        for (int s = 0; s < 11; ++s) r[s] = ldrow(tt0 - 3 + s);
    } else {
#pragma unroll
        for (int s = 0; s < 3; ++s)
            r[s] = first ? make_float4(0.f, 0.f, 0.f, 0.f)
                         : *(const float4*)(xtail_in + (size_t)s * I_DIM + i);
#pragma unroll
        for (int s = 3; s < 11; ++s) r[s] = ldrow(tt0 - 3 + s);
    }

#pragma unroll
    for (int s = 0; s < 8; ++s) {
        float4 y = bb;
        y.x = fmaf(w0.x, r[s].x, y.x); y.x = fmaf(w0.y, r[s+1].x, y.x);
        y.x = fmaf(w0.z, r[s+2].x, y.x); y.x = fmaf(w0.w, r[s+3].x, y.x);
        y.y = fmaf(w1.x, r[s].y, y.y); y.y = fmaf(w1.y, r[s+1].y, y.y);
        y.y = fmaf(w1.z, r[s+2].y, y.y); y.y = fmaf(w1.w, r[s+3].y, y.y);
        y.z = fmaf(w2.x, r[s].z, y.z); y.z = fmaf(w2.y, r[s+1].z, y.z);
        y.z = fmaf(w2.z, r[s+2].z, y.z); y.z = fmaf(w2.w, r[s+3].z, y.z);
        y.w = fmaf(w3.x, r[s].w, y.w); y.w = fmaf(w3.y, r[s+1].w, y.w);
        y.w = fmaf(w3.z, r[s+2].w, y.w); y.w = fmaf(w3.w, r[s+3].w, y.w);
        y.x = y.x / (1.f + __expf(-y.x));
        y.y = y.y / (1.f + __expf(-y.y));
        y.z = y.z / (1.f + __expf(-y.z));
        y.w = y.w / (1.f + __expf(-y.w));
        f16x4v o;
        o[0] = (_Float16)y.x; o[1] = (_Float16)y.y;
        o[2] = (_Float16)y.z; o[3] = (_Float16)y.w;
        *(f16x4v*)(xconv + (size_t)(tt0 + s) * I_DIM + i) = o;
    }

    if (tt0 == LC - 8) {
#pragma unroll
        for (int qq = 0; qq < 3; ++qq)
            *(float4*)(xtail_out + (size_t)qq * I_DIM + i) = r[8 + qq];
    }
}

// ---------------------------------------------------------------------------
// Segment-parallel scan. delta/gate f16 (ld 2I); u (xc) f16.
// ---------------------------------------------------------------------------
__global__ __launch_bounds__(256) void scan_part1(
    const _Float16* __restrict__ delta,
    const float* __restrict__ ssm,
    const _Float16* __restrict__ xc,
    const float* __restrict__ A_log,
    float* __restrict__ aprod,
    float* __restrict__ hend)
{
    __shared__ float Bs[TSEG][16];
    const int tid = threadIdx.x;
    const int i = blockIdx.x * 128 + (tid >> 1);
    const int half = tid & 1;
    const int seg = blockIdx.y;
    const int t0 = seg * TSEG;

    {
        const int tt = tid >> 2, c = (tid & 3) * 4;
        *(float4*)&Bs[tt][c] = *(const float4*)&ssm[(size_t)(t0 + tt) * 160 + 128 + c];
    }
    __syncthreads();

    float Ai[8], h[8], ap[8];
    {
        const float4 a0 = *(const float4*)&A_log[(size_t)i * 16 + half * 8];
        const float4 a1 = *(const float4*)&A_log[(size_t)i * 16 + half * 8 + 4];
        const float al[8] = {a0.x, a0.y, a0.z, a0.w, a1.x, a1.y, a1.z, a1.w};
#pragma unroll
        for (int n = 0; n < 8; ++n) { Ai[n] = -expf(al[n]); h[n] = 0.f; ap[n] = 1.f; }
    }

    float d0 = (float)delta[(size_t)t0 * (2 * I_DIM) + i];
    float u0 = (float)xc[(size_t)t0 * I_DIM + i];
    float d1 = (float)delta[(size_t)(t0 + 1) * (2 * I_DIM) + i];
    float u1 = (float)xc[(size_t)(t0 + 1) * I_DIM + i];
    for (int t = 0; t < TSEG; t += 2) {
        float d2 = 0.f, u2 = 0.f, d3 = 0.f, u3 = 0.f;
        if (t + 3 < TSEG) {
            d2 = (float)delta[(size_t)(t0 + t + 2) * (2 * I_DIM) + i];
            u2 = (float)xc[(size_t)(t0 + t + 2) * I_DIM + i];
            d3 = (float)delta[(size_t)(t0 + t + 3) * (2 * I_DIM) + i];
            u3 = (float)xc[(size_t)(t0 + t + 3) * I_DIM + i];
        }
        {
            const float du = d0 * u0;
#pragma unroll
            for (int n = 0; n < 8; ++n) {
                const float a = __expf(d0 * Ai[n]);
                h[n] = fmaf(h[n], a, du * Bs[t][half * 8 + n]);
                ap[n] *= a;
            }
        }
        {
            const float du = d1 * u1;
#pragma unroll
            for (int n = 0; n < 8; ++n) {
                const float a = __expf(d1 * Ai[n]);
                h[n] = fmaf(h[n], a, du * Bs[t + 1][half * 8 + n]);
                ap[n] *= a;
            }
        }
        d0 = d2; u0 = u2; d1 = d3; u1 = u3;
    }

    const size_t base = (size_t)seg * IN_DIM + (size_t)i * 16 + half * 8;
#pragma unroll
    for (int qq = 0; qq < 2; ++qq) {
        float4 va = {ap[qq * 4 + 0], ap[qq * 4 + 1], ap[qq * 4 + 2], ap[qq * 4 + 3]};
        float4 vh = {h[qq * 4 + 0], h[qq * 4 + 1], h[qq * 4 + 2], h[qq * 4 + 3]};
        *(float4*)&aprod[base + qq * 4] = va;
        *(float4*)&hend[base + qq * 4]  = vh;
    }
}

__global__ __launch_bounds__(256) void scan_part2(
    const float* __restrict__ aprod,
    float* __restrict__ hend,
    float* __restrict__ hstate,
    int first)
{
    const int gid = blockIdx.x * 256 + threadIdx.x;
    float h = first ? 0.f : hstate[gid];
    for (int s = 0; s < SEG; ++s) {
        const size_t idx = (size_t)s * IN_DIM + gid;
        const float ap = aprod[idx];
        const float he = hend[idx];
        hend[idx] = h;
        h = fmaf(ap, h, he);
    }
    hstate[gid] = h;
}

// Phase 3: re-run segment from h_start; z (f16) written in GEMM4 A-panel layout.
__global__ __launch_bounds__(256) void scan_part3(
    const _Float16* __restrict__ delta,
    const _Float16* __restrict__ gate,
    const float* __restrict__ ssm,
    const _Float16* __restrict__ xc,
    _Float16* __restrict__ zPh,
    const float* __restrict__ A_log,
    const float* __restrict__ Dp,
    const float* __restrict__ hstart)  // [SEG][I][N]
{
    __shared__ float BCs[TSEG][32];
    const int tid = threadIdx.x;
    const int i = blockIdx.x * 128 + (tid >> 1);
    const int half = tid & 1;
    const int seg = blockIdx.y;
    const int t0 = seg * TSEG;

    {
        const int tt = tid >> 2, c = (tid & 3) * 8;
        *(float4*)&BCs[tt][c]     = *(const float4*)&ssm[(size_t)(t0 + tt) * 160 + 128 + c];
        *(float4*)&BCs[tt][c + 4] = *(const float4*)&ssm[(size_t)(t0 + tt) * 160 + 132 + c];
    }
    __syncthreads();

    float Ai[8], h[8];
    {
        const float4 a0 = *(const float4*)&A_log[(size_t)i * 16 + half * 8];
        const float4 a1 = *(const float4*)&A_log[(size_t)i * 16 + half * 8 + 4];
        const float al[8] = {a0.x, a0.y, a0.z, a0.w, a1.x, a1.y, a1.z, a1.w};
#pragma unroll
        for (int n = 0; n < 8; ++n) Ai[n] = -expf(al[n]);
        const size_t base = (size_t)seg * IN_DIM + (size_t)i * 16 + half * 8;
        const float4 h0 = *(const float4*)&hstart[base];
        const float4 h1 = *(const float4*)&hstart[base + 4];
        h[0] = h0.x; h[1] = h0.y; h[2] = h0.z; h[3] = h0.w;
        h[4] = h1.x; h[5] = h1.y; h[6] = h1.z; h[7] = h1.w;
    }
    const float Di = Dp[i];

    const int kp = i >> 5, cc = (i >> 3) & 3, jj = i & 7;
    const size_t zb = (size_t)kp * 512 + (size_t)cc * 128 + jj;

    float d0 = (float)delta[(size_t)t0 * (2 * I_DIM) + i];
    float u0 = (float)xc[(size_t)t0 * I_DIM + i];
    float g0 = (float)gate[(size_t)t0 * (2 * I_DIM) + i];
    float d1 = (float)delta[(size_t)(t0 + 1) * (2 * I_DIM) + i];
    float u1 = (float)xc[(size_t)(t0 + 1) * I_DIM + i];
    float g1 = (float)gate[(size_t)(t0 + 1) * (2 * I_DIM) + i];
    for (int t = 0; t < TSEG; t += 2) {
        float d2 = 0.f, u2 = 0.f, g2 = 0.f, d3 = 0.f, u3 = 0.f, g3 = 0.f;
        if (t + 3 < TSEG) {
            d2 = (float)delta[(size_t)(t0 + t + 2) * (2 * I_DIM) + i];
            u2 = (float)xc[(size_t)(t0 + t + 2) * I_DIM + i];
            g2 = (float)gate[(size_t)(t0 + t + 2) * (2 * I_DIM) + i];
            d3 = (float)delta[(size_t)(t0 + t + 3) * (2 * I_DIM) + i];
            u3 = (float)xc[(size_t)(t0 + t + 3) * I_DIM + i];
            g3 = (float)gate[(size_t)(t0 + t + 3) * (2 * I_DIM) + i];
        }
#pragma unroll
        for (int ss = 0; ss < 2; ++ss) {
            const float d = ss ? d1 : d0;
            const float u = ss ? u1 : u0;
            const float g = ss ? g1 : g0;
            const int tt = t + ss;
            const float du = d * u;
            float y = 0.f;
#pragma unroll
            for (int n = 0; n < 8; ++n) {
                const float a = __expf(d * Ai[n]);
                h[n] = fmaf(h[n], a, du * BCs[tt][half * 8 + n]);
                y = fmaf(h[n], BCs[tt][16 + half * 8 + n], y);
            }
            y += __shfl_xor(y, 1);
            if (half == 0) {
                const float sg = g / (1.f + __expf(-g));
                const float zv = (y + u * Di) * sg;
                const int row = t0 + tt;
                zPh[((size_t)(row >> 4) * (I_DIM >> 5)) * 512 + zb + (size_t)(row & 15) * 8]
                    = (_Float16)zv;
            }
        }
        d0 = d2; u0 = u2; g0 = g2; d1 = d3; u1 = u3; g1 = g3;
    }
}

// ---------------------------------------------------------------------------
extern "C" void kernel_launch(void* const* d_in, const int* in_sizes, int n_in,
                              void* d_out, int out_size, void* d_ws, size_t ws_size,
                              hipStream_t stream)
{
    const float* hs      = (const float*)d_in[0];
    const float* W_in    = (const float*)d_in[1];
    const float* conv_w  = (const float*)d_in[2];
    const float* conv_b  = (const float*)d_in[3];
    const float* W_x     = (const float*)d_in[4];
    const float* W_dt    = (const float*)d_in[5];
    const float* dt_bias = (const float*)d_in[6];
    const float* A_log   = (const float*)d_in[7];
    const float* Dp      = (const float*)d_in[8];
    const float* W_out   = (const float*)d_in[9];
    float* out = (float*)d_out;

    // workspace layout (~223 MB)
    char* p = (char*)d_ws;
    auto alloc = [&](size_t bytes) {
        char* r = p;
        p += (bytes + 255) & ~(size_t)255;
        return r;
    };
    _Float16* proj16 = (_Float16*)alloc((size_t)68 * 1024 * 1024);
    _Float16* xconv16 = (_Float16*)alloc((size_t)LC * I_DIM * 2);  // 32 MB
    float* ssm    = (float*)alloc((size_t)LC * 160 * 4);           // 2.6 MB
    float* xtail  = (float*)alloc((size_t)2 * 3 * I_DIM * 4);
    float* hstate = (float*)alloc((size_t)IN_DIM * 4);
    _Float16* WinPh  = (_Float16*)alloc((size_t)2 * I_DIM * H_DIM * 2);  // 32 MB
    _Float16* WoutPh = (_Float16*)alloc((size_t)H_DIM * I_DIM * 2);      // 16 MB
    _Float16* WdtPh  = (_Float16*)alloc((size_t)I_DIM * R_DIM * 2);
    _Float16* WdtPl  = (_Float16*)alloc((size_t)I_DIM * R_DIM * 2);
    _Float16* WxPh   = (_Float16*)alloc((size_t)256 * I_DIM * 2);
    _Float16* WxPl   = (_Float16*)alloc((size_t)256 * I_DIM * 2);
    _Float16* hsPh   = (_Float16*)alloc((size_t)L_DIM * H_DIM * 2);  // 33.5 MB
    _Float16* zPh    = (_Float16*)alloc((size_t)LC * I_DIM * 2);     // 32 MB

    const dim3 blk(256);
    const int NSSM = R_DIM + 2 * N_DIM;  // 160

    // ---- pack weights + full hs into panel format (once per launch) ----
    pack_bp<<<dim3(2 * I_DIM / 32, H_DIM / 32), dim3(128), 0, stream>>>(
        W_in, WinPh, nullptr, H_DIM, 2 * I_DIM);
    pack_bp<<<dim3(H_DIM / 32, I_DIM / 32), dim3(128), 0, stream>>>(
        W_out, WoutPh, nullptr, I_DIM, H_DIM);
    pack_bp<<<dim3(I_DIM / 32, R_DIM / 32), dim3(128), 0, stream>>>(
        W_dt, WdtPh, WdtPl, R_DIM, I_DIM);
    pack_bp<<<dim3(NSSM / 32, I_DIM / 32), dim3(128), 0, stream>>>(
        W_x, WxPh, WxPl, I_DIM, NSSM);
    pack_ap<<<dim3(L_DIM / 16, H_DIM / 128), blk, 0, stream>>>(
        hs, H_DIM, hsPh, H_DIM);

    for (int c = 0; c < NCHUNK; ++c) {
        const int t0 = c * LC;
        const int first = (c == 0) ? 1 : 0;
        float* out_c = out + (size_t)t0 * H_DIM;
        float* aprod = out_c;                 // scan scratch in out region
        float* hend  = out_c + (size_t)SEG * IN_DIM;  // exact fit: 2*SEG*IN = LC*H
        float* xtA = xtail + (size_t)(c & 1) * 3 * I_DIM;
        float* xtB = xtail + (size_t)((c & 1) ^ 1) * 3 * I_DIM;
        const _Float16* hsPh_c = hsPh + (size_t)(t0 >> 4) * (H_DIM >> 5) * 512;

        // 1) proj(f16) = hs_c @ W_in  (512 blocks)
        gemm_r256<1><<<dim3(512, 1), dim3(512), 0, stream>>>(
            hsPh_c, WinPh, proj16, 2 * I_DIM, H_DIM, LC / 256, H_DIM, 0);

        // 2) xconv(f16) = silu(dwconv(x_pre) + b); zeroes ssm; saves tail
        conv_silu_kernel<<<dim3((LC / 8) * (I_DIM / 4) / 256), blk, 0, stream>>>(
            proj16, xtA, xtB, conv_w, conv_b, xconv16, ssm, first);

        // 3) ssm = xconv @ W_x  (f16 A direct, B split, split-K x8, atomics)
        gemm_p<0, 3, 0, 1, true, 0><<<dim3(2 * (LC / 128), 8), blk, 0, stream>>>(
            xconv16, I_DIM, nullptr, WxPh, WxPl, ssm, NSSM,
            I_DIM, NSSM, LC / 128, I_DIM / 8, nullptr);

        // 4) delta(f16) = softplus(ssm[:, :R] @ W_dt + dt_bias) -> proj x-half
        gemm_p<1, 0, 1, 1, false, 1><<<dim3(32 * (LC / 128), 1), blk, 0, stream>>>(
            ssm, NSSM, nullptr, WdtPh, WdtPl, proj16, 2 * I_DIM,
            R_DIM, 0, LC / 128, R_DIM, dt_bias);

        // 5) segment-parallel scan; z -> zPh panels
        scan_part1<<<dim3(I_DIM / 128, SEG), blk, 0, stream>>>(
            proj16, ssm, xconv16, A_log, aprod, hend);
        scan_part2<<<dim3(IN_DIM / 256), blk, 0, stream>>>(
            aprod, hend, hstate, first);
        scan_part3<<<dim3(I_DIM / 128, SEG), blk, 0, stream>>>(
            proj16, proj16 + I_DIM, ssm, xconv16, zPh, A_log, Dp, hend);

        // 6) GEMM4 partials (f16): 2 k-slices of z @ W_out into proj region
        gemm_r256<1><<<dim3((LC / 256) * (H_DIM / 256), 2), dim3(512), 0, stream>>>(
            zPh, WoutPh, proj16, H_DIM, I_DIM, LC / 256,
            I_DIM / 2, (size_t)LC * H_DIM);

        // 7) out_c = P0+P1
        reduce2_f16_kernel<<<dim3(LC * H_DIM / 2048), blk, 0, stream>>>(
            proj16, out_c);
    }
}

// Round 22
// 981.278 us; speedup vs baseline: 5.7729x; 1.0064x over previous
//
#include <hip/hip_runtime.h>
#include <cmath>
#include <stdint.h>

#define H_DIM 2048
#define I_DIM 4096
#define N_DIM 16
#define R_DIM 128
#define K_CONV 4
#define L_DIM 8192
#define LC 4096                 // chunk length
#define NCHUNK (L_DIM / LC)
#define SEG 64                  // scan segments per chunk
#define TSEG (LC / SEG)         // 64 steps per segment
#define IN_DIM (I_DIM * N_DIM)  // 65536 recurrences

typedef _Float16 f16x8 __attribute__((ext_vector_type(8)));
typedef _Float16 f16x4v __attribute__((ext_vector_type(4)));
typedef float    f32x4 __attribute__((ext_vector_type(4)));

// direct HBM->LDS, 16B per lane; LDS base must be wave-uniform (HW adds lane*16)
__device__ __forceinline__ void gl_lds(const _Float16* g, _Float16* lbase, int lane) {
#if __has_builtin(__builtin_amdgcn_global_load_lds)
    __builtin_amdgcn_global_load_lds(
        (const __attribute__((address_space(1))) void*)g,
        (__attribute__((address_space(3))) void*)lbase, 16, 0, 0);
#else
    *(f16x8*)&lbase[lane * 8] = *(const f16x8*)g;
#endif
}

// ---------------------------------------------------------------------------
// 256x256 panel GEMM (GEMM1 & GEMM4): A direct global->VGPR (panel layout is
// fragment-ordered), B staged in LDS via 3-buffer counted-vmcnt gl_lds.
// 512 threads = 8 waves (4m x 2n), wave tile 64x128, acc[4][8]. BK=32.
// LDS = 48KB. launch_bounds(512,2): acc[4][8] needs >=160 VGPR; (512,4)
// forces 64 VGPR and spills the accumulator (round-19: 8.6 GB scratch
// traffic/dispatch). Do NOT raise this.
// XCD-balanced supertiles: xcd = orig&7 owns an sm x sn tile rectangle
// (sm*sn = gridDim.x/8; (gm/sm)*(gn/sn) = 8) -> per-XCD unique working set
// balanced between A and B strips for L2 reuse.
// Steady wait: B(k+1)2 + B(k+2)2 + A(k+1)4 in flight -> vmcnt(8).
// Split-K via blockIdx.y*kchunk, partials at C + y*partStride. OUTF16 store.
// Requires KT = kchunk/32 even and >= 4.
// ---------------------------------------------------------------------------
template <int OUTF16>
__global__ __launch_bounds__(512, 2) void gemm_r256(
    const _Float16* __restrict__ Aph,
    const _Float16* __restrict__ Bph,
    void* __restrict__ Cv, int ldc, int Kd, int gm,
    int sm, int sn,
    int kchunk, size_t partStride)
{
    __shared__ __align__(16) _Float16 Bs[3][8192];  // [buf][16 n-panels]

    const int tid = threadIdx.x;
    // balanced-rectangle XCD decomposition (bijective; grid = 8*sm*sn)
    const int xcd = blockIdx.x & 7;
    const int t   = blockIdx.x >> 3;
    const int gmdiv = gm / sm;
    const int mr = xcd % gmdiv, nr = xcd / gmdiv;
    const int m0 = (mr * sm + (t % sm)) * 256;
    const int n0 = (nr * sn + (t / sm)) * 256;
    const int kbeg = blockIdx.y * kchunk;

    const int w = tid >> 6, l = tid & 63;
    const int wm = w & 3, wn = w >> 2;   // 4m x 2n waves
    const int lr = l & 15, lg = l >> 4;

    const int KP = Kd >> 5;
    const int np0 = n0 >> 4, mp0 = m0 >> 4;

    f32x4 acc[4][8];
#pragma unroll
    for (int a = 0; a < 4; ++a)
#pragma unroll
        for (int b = 0; b < 8; ++b) acc[a][b] = (f32x4){0.f, 0.f, 0.f, 0.f};

    // wave's 4 A row-panels: mp0 + wm*4 + t
    const _Float16* Abase = Aph + ((size_t)(mp0 + wm * 4) * KP) * 512 + (size_t)l * 8;
    const size_t Astride = (size_t)KP * 512;

    f16x8 faA[4], faB[4];

    auto loadA = [&](int k0, f16x8* fa) {
        const size_t ko = (size_t)(k0 >> 5) * 512;
#pragma unroll
        for (int tt = 0; tt < 4; ++tt)
            fa[tt] = *(const f16x8*)(Abase + (size_t)tt * Astride + ko);
    };
    auto stageB = [&](int k0, int p) {   // 2 gl_lds / thread
        const int kp = k0 >> 5;
#pragma unroll
        for (int s = 0; s < 2; ++s) {
            const int st = w + s * 8;
            gl_lds(Bph + ((size_t)(np0 + st) * KP + kp) * 512 + (size_t)l * 8,
                   &Bs[p][st * 512], l);
        }
    };
    auto domfma = [&](int p, f16x8* fa) {
        f16x8 fb[8];
#pragma unroll
        for (int nt = 0; nt < 8; ++nt)
            fb[nt] = *(const f16x8*)&Bs[p][(wn * 8 + nt) * 512 + l * 8];
        __builtin_amdgcn_s_setprio(1);
#pragma unroll
        for (int mt = 0; mt < 4; ++mt)
#pragma unroll
            for (int nt = 0; nt < 8; ++nt)
                acc[mt][nt] = __builtin_amdgcn_mfma_f32_16x16x32_f16(
                    fa[mt], fb[nt], acc[mt][nt], 0, 0, 0);
        __builtin_amdgcn_s_setprio(0);
    };

    const int KT = kchunk >> 5;          // even, >= 4
    stageB(kbeg, 0);
    stageB(kbeg + 32, 1);
    loadA(kbeg, faA);

    int k = 0;
    for (; k + 3 < KT; k += 2) {
        stageB(kbeg + (k + 2) * 32, (k + 2) % 3);
        loadA(kbeg + (k + 1) * 32, faB);
        asm volatile("s_waitcnt vmcnt(8)" ::: "memory");
        __builtin_amdgcn_s_barrier();
        __builtin_amdgcn_sched_barrier(0);
        domfma(k % 3, faA);
        __builtin_amdgcn_s_barrier();

        stageB(kbeg + (k + 3) * 32, (k + 3) % 3);
        loadA(kbeg + (k + 2) * 32, faA);
        asm volatile("s_waitcnt vmcnt(8)" ::: "memory");
        __builtin_amdgcn_s_barrier();
        __builtin_amdgcn_sched_barrier(0);
        domfma((k + 1) % 3, faB);
        __builtin_amdgcn_s_barrier();
    }
    // k == KT-2
    loadA(kbeg + (KT - 1) * 32, faB);
    asm volatile("s_waitcnt vmcnt(4)" ::: "memory");
    __builtin_amdgcn_s_barrier();
    __builtin_amdgcn_sched_barrier(0);
    domfma((KT - 2) % 3, faA);
    __builtin_amdgcn_s_barrier();
    asm volatile("s_waitcnt vmcnt(0)" ::: "memory");
    __builtin_amdgcn_s_barrier();
    __builtin_amdgcn_sched_barrier(0);
    domfma((KT - 1) % 3, faB);

#pragma unroll
    for (int mt = 0; mt < 4; ++mt) {
        const int row = m0 + wm * 64 + mt * 16 + lg * 4;
#pragma unroll
        for (int nt = 0; nt < 8; ++nt) {
            const int col = n0 + wn * 128 + nt * 16 + lr;
#pragma unroll
            for (int j = 0; j < 4; ++j) {
                if (OUTF16) {
                    _Float16* C = (_Float16*)Cv + (size_t)blockIdx.y * partStride;
                    C[(size_t)(row + j) * ldc + col] = (_Float16)acc[mt][nt][j];
                } else {
                    float* C = (float*)Cv + (size_t)blockIdx.y * partStride;
                    C[(size_t)(row + j) * ldc + col] = acc[mt][nt][j];
                }
            }
        }
    }
}

// ---------------------------------------------------------------------------
// out = P0+P1 (f16 partials, f32 out), 8 elems / thread.
// ---------------------------------------------------------------------------
__global__ __launch_bounds__(256) void reduce2_f16_kernel(
    const _Float16* __restrict__ P, float* __restrict__ out)
{
    const size_t idx = ((size_t)blockIdx.x * 256 + threadIdx.x) * 8;
    const size_t S = (size_t)LC * H_DIM;
    const f16x8 a = *(const f16x8*)(P + idx);
    const f16x8 b = *(const f16x8*)(P + S + idx);
    float r[8];
#pragma unroll
    for (int j = 0; j < 8; ++j)
        r[j] = (float)a[j] + (float)b[j];
    *(float4*)(out + idx)     = *(float4*)&r[0];
    *(float4*)(out + idx + 4) = *(float4*)&r[4];
}

// ---------------------------------------------------------------------------
// 128x128 panel GEMM (GEMM2/3), 2-buffer schedule.
// AK=0: fp32 A reg-split. AK=3: f16 A rows, hi-only, no cvt (xconv path).
// ASPLIT/BSPLIT lo-correction; OUTF16: store f16 (non-atomic only).
// ---------------------------------------------------------------------------
template <int EPI, int AK, int ASPLIT, int BSPLIT, bool ATOMIC, int OUTF16>
__global__ __launch_bounds__(256, ASPLIT ? 2 : (BSPLIT ? 3 : 4)) void gemm_p(
    const void* __restrict__ Av, int lda,
    const _Float16* __restrict__ Aph,
    const _Float16* __restrict__ Bph, const _Float16* __restrict__ Bpl,
    void* __restrict__ Cv, int ldc,
    int Kd, int Ncap, int gm, int kchunk,
    const float* __restrict__ bias)
{
    constexpr int S_AH = 0;
    constexpr int S_AL = ASPLIT ? 1 : 0;
    constexpr int S_BH = ASPLIT ? 2 : 1;
    constexpr int S_BL = S_BH + 1;
    constexpr int NSLOT = S_BH + 1 + BSPLIT;
    __shared__ __align__(16) _Float16 Sh[2][NSLOT][4096];

    const int tid = threadIdx.x;
    int bid = blockIdx.x;
    const int q = gridDim.x >> 3;
    bid = (bid & 7) * q + (bid >> 3);
    const int m0 = (bid % gm) * 128;
    const int n0 = (bid / gm) * 128;

    const int kbeg = blockIdx.y * kchunk;
    const int kend = (kbeg + kchunk < Kd) ? (kbeg + kchunk) : Kd;

    const int w = tid >> 6, l = tid & 63;
    const int wm = w & 1, wn = w >> 1;
    const int lr = l & 15, lg = l >> 4;

    const int ar = tid >> 1, ah = tid & 1;
    const int aw0 = (ar >> 4) * 512 + (((ah * 2) * 16 + (ar & 15)) * 8);
    const int aw1 = aw0 + 128;

    const int KP = Kd >> 5;
    const int np0 = n0 >> 4;

    f32x4 acc[4][4];
#pragma unroll
    for (int a = 0; a < 4; ++a)
#pragma unroll
        for (int b = 0; b < 4; ++b) acc[a][b] = (f32x4){0.f, 0.f, 0.f, 0.f};

    float xf[16];
    f16x8 sah[2], sal[2];

    auto issueA = [&](int k0) {
        if (AK == 0) {
            const float* Ap = (const float*)Av + (size_t)(m0 + ar) * lda + k0 + ah * 16;
            *(float4*)&xf[0]  = *(const float4*)(Ap + 0);
            *(float4*)&xf[4]  = *(const float4*)(Ap + 4);
            *(float4*)&xf[8]  = *(const float4*)(Ap + 8);
            *(float4*)&xf[12] = *(const float4*)(Ap + 12);
        } else if (AK == 3) {
            const _Float16* Ap = (const _Float16*)Av + (size_t)(m0 + ar) * lda + k0 + ah * 16;
            sah[0] = *(const f16x8*)(Ap + 0);
            sah[1] = *(const f16x8*)(Ap + 8);
        }
    };
    auto cvtA = [&]() {
        if (AK == 0) {
#pragma unroll
            for (int c2 = 0; c2 < 2; ++c2)
#pragma unroll
                for (int j = 0; j < 8; ++j) {
                    const float xv = xf[c2 * 8 + j];
                    const _Float16 h = (_Float16)xv;
                    sah[c2][j] = h;
                    if (ASPLIT) sal[c2][j] = (_Float16)(xv - (float)h);
                }
        }
    };
    auto writeA = [&](int p) {
        *(f16x8*)&Sh[p][S_AH][aw0] = sah[0];
        *(f16x8*)&Sh[p][S_AH][aw1] = sah[1];
        if (ASPLIT) {
            *(f16x8*)&Sh[p][S_AL][aw0] = sal[0];
            *(f16x8*)&Sh[p][S_AL][aw1] = sal[1];
        }
    };
    auto stageGL = [&](int k0, int p) {
        const int kp = k0 >> 5;
#pragma unroll
        for (int qq = 0; qq < 2; ++qq) {
            const int st = 2 * w + qq;
            const size_t go = ((size_t)(np0 + st) * KP + kp) * 512 + (size_t)l * 8;
            gl_lds(Bph + go, &Sh[p][S_BH][st * 512], l);
            if (BSPLIT) gl_lds(Bpl + go, &Sh[p][S_BL][st * 512], l);
        }
    };
    auto domfma = [&](int b) {
        f16x8 fah[4], fal[4], fbh[4], fbl[4];
#pragma unroll
        for (int t = 0; t < 4; ++t) {
            fah[t] = *(const f16x8*)&Sh[b][S_AH][(wm * 4 + t) * 512 + l * 8];
            if (ASPLIT) fal[t] = *(const f16x8*)&Sh[b][S_AL][(wm * 4 + t) * 512 + l * 8];
            fbh[t] = *(const f16x8*)&Sh[b][S_BH][(wn * 4 + t) * 512 + l * 8];
            if (BSPLIT) fbl[t] = *(const f16x8*)&Sh[b][S_BL][(wn * 4 + t) * 512 + l * 8];
        }
        __builtin_amdgcn_s_setprio(1);
#pragma unroll
        for (int mt = 0; mt < 4; ++mt)
#pragma unroll
            for (int nt = 0; nt < 4; ++nt) {
                f32x4& a = acc[mt][nt];
                a = __builtin_amdgcn_mfma_f32_16x16x32_f16(fah[mt], fbh[nt], a, 0, 0, 0);
                if (BSPLIT)
                    a = __builtin_amdgcn_mfma_f32_16x16x32_f16(fah[mt], fbl[nt], a, 0, 0, 0);
                if (ASPLIT)
                    a = __builtin_amdgcn_mfma_f32_16x16x32_f16(fal[mt], fbh[nt], a, 0, 0, 0);
            }
        __builtin_amdgcn_s_setprio(0);
    };

    issueA(kbeg); cvtA(); writeA(0);
    stageGL(kbeg, 0);
    __syncthreads();
    int p = 0;
    for (int k0 = kbeg; k0 < kend; k0 += 32) {
        const bool more = (k0 + 32 < kend);
        if (more) {
            issueA(k0 + 32);
            stageGL(k0 + 32, p ^ 1);
        }
        domfma(p);
        if (more) { cvtA(); writeA(p ^ 1); }
        __syncthreads();
        p ^= 1;
    }

#pragma unroll
    for (int mt = 0; mt < 4; ++mt) {
        const int row = m0 + wm * 64 + mt * 16 + lg * 4;
#pragma unroll
        for (int nt = 0; nt < 4; ++nt) {
            const int col = n0 + wn * 64 + nt * 16 + lr;
            if (Ncap == 0 || col < Ncap) {
#pragma unroll
                for (int j = 0; j < 4; ++j) {
                    float v = acc[mt][nt][j];
                    if (EPI == 1) {
                        v += bias[col];
                        v = (v > 20.f) ? v : __logf(1.f + __expf(v));
                    }
                    const size_t off = (size_t)(row + j) * ldc + col;
                    if (ATOMIC)      atomicAdd(&((float*)Cv)[off], v);
                    else if (OUTF16) ((_Float16*)Cv)[off] = (_Float16)v;
                    else             ((float*)Cv)[off] = v;
                }
            }
        }
    }
}

// ---------------------------------------------------------------------------
// Pack W [Kd][Nd] fp32 -> f16 B-panels [Nd/16][Kd/32][512]; lo only if Pl.
// ---------------------------------------------------------------------------
__global__ __launch_bounds__(128) void pack_bp(
    const float* __restrict__ W, _Float16* __restrict__ Ph,
    _Float16* __restrict__ Pl, int Kd, int Nd)
{
    __shared__ float t[32][33];
    const int tid = threadIdx.x;
    const int n0 = blockIdx.x * 32, k0 = blockIdx.y * 32;
#pragma unroll
    for (int h = 0; h < 2; ++h) {
        const int qd = tid + h * 128;
        const int kk = qd >> 3, qq = qd & 7;
        *(float4*)&t[kk][qq * 4] = *(const float4*)(W + (size_t)(k0 + kk) * Nd + n0 + qq * 4);
    }
    __syncthreads();
    const int c = tid >> 5, nn = tid & 31;
    const int np = (n0 + nn) >> 4;
    const int r  = nn & 15;
    const int kp = k0 >> 5;
    const size_t base = ((size_t)np * (Kd >> 5) + kp) * 512 + (c * 16 + r) * 8;
    f16x8 vh, vl;
#pragma unroll
    for (int j = 0; j < 8; ++j) {
        const float v = t[c * 8 + j][nn];
        const _Float16 h = (_Float16)v;
        vh[j] = h;
        vl[j] = (_Float16)(v - (float)h);
    }
    *(f16x8*)&Ph[base] = vh;
    if (Pl) *(f16x8*)&Pl[base] = vl;
}

// ---------------------------------------------------------------------------
// Pack A fp32 [M][K] row-major -> hi f16 A-panels [M/16][K/32][512].
// ---------------------------------------------------------------------------
__global__ __launch_bounds__(256) void pack_ap(
    const float* __restrict__ A, int lda,
    _Float16* __restrict__ Ph, int Kd)
{
    const int tid = threadIdx.x;
    const int mp = blockIdx.x;
    const int r = tid >> 4, c8 = tid & 15;
    const int k0 = blockIdx.y * 128 + c8 * 8;
    const float* Ap = A + (size_t)(mp * 16 + r) * lda + k0;
    const float4 v0 = *(const float4*)Ap;
    const float4 v1 = *(const float4*)(Ap + 4);
    const float x[8] = {v0.x, v0.y, v0.z, v0.w, v1.x, v1.y, v1.z, v1.w};
    f16x8 vh;
#pragma unroll
    for (int j = 0; j < 8; ++j) vh[j] = (_Float16)x[j];
    const int kp = k0 >> 5;
    const int c  = (k0 >> 3) & 3;
    const size_t base = ((size_t)mp * (Kd >> 5) + kp) * 512 + (c * 16 + r) * 8;
    *(f16x8*)&Ph[base] = vh;
}

// ---------------------------------------------------------------------------
// Causal depthwise conv (K=4) + bias + silu (4ch x 8t / thread); zeroes ssm.
// proj (x-half) f16 ld 2I; xconv written f16. Tail saved f32.
// ---------------------------------------------------------------------------
__global__ __launch_bounds__(256) void conv_silu_kernel(
    const _Float16* __restrict__ proj,
    const float* __restrict__ xtail_in,
    float* __restrict__ xtail_out,
    const float* __restrict__ w,
    const float* __restrict__ b,
    _Float16* __restrict__ xconv,
    float* __restrict__ ssm,
    int first)
{
    const int gid = blockIdx.x * 256 + threadIdx.x;
    if (gid < (LC * 160) / 4)
        *(float4*)(ssm + (size_t)gid * 4) = make_float4(0.f, 0.f, 0.f, 0.f);

    const int i4 = gid & (I_DIM / 4 - 1);
    const int t8 = gid >> 10;
    const int i = i4 * 4;
    const int tt0 = t8 * 8;

    const float4 w0 = *(const float4*)(w + (size_t)(i + 0) * 4);
    const float4 w1 = *(const float4*)(w + (size_t)(i + 1) * 4);
    const float4 w2 = *(const float4*)(w + (size_t)(i + 2) * 4);
    const float4 w3 = *(const float4*)(w + (size_t)(i + 3) * 4);
    const float4 bb = *(const float4*)(b + i);

    auto ldrow = [&](int row) -> float4 {
        const f16x4v v = *(const f16x4v*)(proj + (size_t)row * (2 * I_DIM) + i);
        return make_float4((float)v[0], (float)v[1], (float)v[2], (float)v[3]);
    };

    float4 r[11];
    if (tt0 >= 3) {
#pragma unroll
        for (int s = 0; s < 11; ++s) r[s] = ldrow(tt0 - 3 + s);
    } else {
#pragma unroll
        for (int s = 0; s < 3; ++s)
            r[s] = first ? make_float4(0.f, 0.f, 0.f, 0.f)
                         : *(const float4*)(xtail_in + (size_t)s * I_DIM + i);
#pragma unroll
        for (int s = 3; s < 11; ++s) r[s] = ldrow(tt0 - 3 + s);
    }

#pragma unroll
    for (int s = 0; s < 8; ++s) {
        float4 y = bb;
        y.x = fmaf(w0.x, r[s].x, y.x); y.x = fmaf(w0.y, r[s+1].x, y.x);
        y.x = fmaf(w0.z, r[s+2].x, y.x); y.x = fmaf(w0.w, r[s+3].x, y.x);
        y.y = fmaf(w1.x, r[s].y, y.y); y.y = fmaf(w1.y, r[s+1].y, y.y);
        y.y = fmaf(w1.z, r[s+2].y, y.y); y.y = fmaf(w1.w, r[s+3].y, y.y);
        y.z = fmaf(w2.x, r[s].z, y.z); y.z = fmaf(w2.y, r[s+1].z, y.z);
        y.z = fmaf(w2.z, r[s+2].z, y.z); y.z = fmaf(w2.w, r[s+3].z, y.z);
        y.w = fmaf(w3.x, r[s].w, y.w); y.w = fmaf(w3.y, r[s+1].w, y.w);
        y.w = fmaf(w3.z, r[s+2].w, y.w); y.w = fmaf(w3.w, r[s+3].w, y.w);
        y.x = y.x / (1.f + __expf(-y.x));
        y.y = y.y / (1.f + __expf(-y.y));
        y.z = y.z / (1.f + __expf(-y.z));
        y.w = y.w / (1.f + __expf(-y.w));
        f16x4v o;
        o[0] = (_Float16)y.x; o[1] = (_Float16)y.y;
        o[2] = (_Float16)y.z; o[3] = (_Float16)y.w;
        *(f16x4v*)(xconv + (size_t)(tt0 + s) * I_DIM + i) = o;
    }

    if (tt0 == LC - 8) {
#pragma unroll
        for (int qq = 0; qq < 3; ++qq)
            *(float4*)(xtail_out + (size_t)qq * I_DIM + i) = r[8 + qq];
    }
}

// ---------------------------------------------------------------------------
// Segment-parallel scan. delta/gate f16 (ld 2I); u (xc) f16.
// ---------------------------------------------------------------------------
__global__ __launch_bounds__(256) void scan_part1(
    const _Float16* __restrict__ delta,
    const float* __restrict__ ssm,
    const _Float16* __restrict__ xc,
    const float* __restrict__ A_log,
    float* __restrict__ aprod,
    float* __restrict__ hend)
{
    __shared__ float Bs[TSEG][16];
    const int tid = threadIdx.x;
    const int i = blockIdx.x * 128 + (tid >> 1);
    const int half = tid & 1;
    const int seg = blockIdx.y;
    const int t0 = seg * TSEG;

    {
        const int tt = tid >> 2, c = (tid & 3) * 4;
        *(float4*)&Bs[tt][c] = *(const float4*)&ssm[(size_t)(t0 + tt) * 160 + 128 + c];
    }
    __syncthreads();

    float Ai[8], h[8], ap[8];
    {
        const float4 a0 = *(const float4*)&A_log[(size_t)i * 16 + half * 8];
        const float4 a1 = *(const float4*)&A_log[(size_t)i * 16 + half * 8 + 4];
        const float al[8] = {a0.x, a0.y, a0.z, a0.w, a1.x, a1.y, a1.z, a1.w};
#pragma unroll
        for (int n = 0; n < 8; ++n) { Ai[n] = -expf(al[n]); h[n] = 0.f; ap[n] = 1.f; }
    }

    float d0 = (float)delta[(size_t)t0 * (2 * I_DIM) + i];
    float u0 = (float)xc[(size_t)t0 * I_DIM + i];
    float d1 = (float)delta[(size_t)(t0 + 1) * (2 * I_DIM) + i];
    float u1 = (float)xc[(size_t)(t0 + 1) * I_DIM + i];
    for (int t = 0; t < TSEG; t += 2) {
        float d2 = 0.f, u2 = 0.f, d3 = 0.f, u3 = 0.f;
        if (t + 3 < TSEG) {
            d2 = (float)delta[(size_t)(t0 + t + 2) * (2 * I_DIM) + i];
            u2 = (float)xc[(size_t)(t0 + t + 2) * I_DIM + i];
            d3 = (float)delta[(size_t)(t0 + t + 3) * (2 * I_DIM) + i];
            u3 = (float)xc[(size_t)(t0 + t + 3) * I_DIM + i];
        }
        {
            const float du = d0 * u0;
#pragma unroll
            for (int n = 0; n < 8; ++n) {
                const float a = __expf(d0 * Ai[n]);
                h[n] = fmaf(h[n], a, du * Bs[t][half * 8 + n]);
                ap[n] *= a;
            }
        }
        {
            const float du = d1 * u1;
#pragma unroll
            for (int n = 0; n < 8; ++n) {
                const float a = __expf(d1 * Ai[n]);
                h[n] = fmaf(h[n], a, du * Bs[t + 1][half * 8 + n]);
                ap[n] *= a;
            }
        }
        d0 = d2; u0 = u2; d1 = d3; u1 = u3;
    }

    const size_t base = (size_t)seg * IN_DIM + (size_t)i * 16 + half * 8;
#pragma unroll
    for (int qq = 0; qq < 2; ++qq) {
        float4 va = {ap[qq * 4 + 0], ap[qq * 4 + 1], ap[qq * 4 + 2], ap[qq * 4 + 3]};
        float4 vh = {h[qq * 4 + 0], h[qq * 4 + 1], h[qq * 4 + 2], h[qq * 4 + 3]};
        *(float4*)&aprod[base + qq * 4] = va;
        *(float4*)&hend[base + qq * 4]  = vh;
    }
}

__global__ __launch_bounds__(256) void scan_part2(
    const float* __restrict__ aprod,
    float* __restrict__ hend,
    float* __restrict__ hstate,
    int first)
{
    const int gid = blockIdx.x * 256 + threadIdx.x;
    float h = first ? 0.f : hstate[gid];
    for (int s = 0; s < SEG; ++s) {
        const size_t idx = (size_t)s * IN_DIM + gid;
        const float ap = aprod[idx];
        const float he = hend[idx];
        hend[idx] = h;
        h = fmaf(ap, h, he);
    }
    hstate[gid] = h;
}

// Phase 3: re-run segment from h_start; z (f16) written in GEMM4 A-panel layout.
__global__ __launch_bounds__(256) void scan_part3(
    const _Float16* __restrict__ delta,
    const _Float16* __restrict__ gate,
    const float* __restrict__ ssm,
    const _Float16* __restrict__ xc,
    _Float16* __restrict__ zPh,
    const float* __restrict__ A_log,
    const float* __restrict__ Dp,
    const float* __restrict__ hstart)  // [SEG][I][N]
{
    __shared__ float BCs[TSEG][32];
    const int tid = threadIdx.x;
    const int i = blockIdx.x * 128 + (tid >> 1);
    const int half = tid & 1;
    const int seg = blockIdx.y;
    const int t0 = seg * TSEG;

    {
        const int tt = tid >> 2, c = (tid & 3) * 8;
        *(float4*)&BCs[tt][c]     = *(const float4*)&ssm[(size_t)(t0 + tt) * 160 + 128 + c];
        *(float4*)&BCs[tt][c + 4] = *(const float4*)&ssm[(size_t)(t0 + tt) * 160 + 132 + c];
    }
    __syncthreads();

    float Ai[8], h[8];
    {
        const float4 a0 = *(const float4*)&A_log[(size_t)i * 16 + half * 8];
        const float4 a1 = *(const float4*)&A_log[(size_t)i * 16 + half * 8 + 4];
        const float al[8] = {a0.x, a0.y, a0.z, a0.w, a1.x, a1.y, a1.z, a1.w};
#pragma unroll
        for (int n = 0; n < 8; ++n) Ai[n] = -expf(al[n]);
        const size_t base = (size_t)seg * IN_DIM + (size_t)i * 16 + half * 8;
        const float4 h0 = *(const float4*)&hstart[base];
        const float4 h1 = *(const float4*)&hstart[base + 4];
        h[0] = h0.x; h[1] = h0.y; h[2] = h0.z; h[3] = h0.w;
        h[4] = h1.x; h[5] = h1.y; h[6] = h1.z; h[7] = h1.w;
    }
    const float Di = Dp[i];

    const int kp = i >> 5, cc = (i >> 3) & 3, jj = i & 7;
    const size_t zb = (size_t)kp * 512 + (size_t)cc * 128 + jj;

    float d0 = (float)delta[(size_t)t0 * (2 * I_DIM) + i];
    float u0 = (float)xc[(size_t)t0 * I_DIM + i];
    float g0 = (float)gate[(size_t)t0 * (2 * I_DIM) + i];
    float d1 = (float)delta[(size_t)(t0 + 1) * (2 * I_DIM) + i];
    float u1 = (float)xc[(size_t)(t0 + 1) * I_DIM + i];
    float g1 = (float)gate[(size_t)(t0 + 1) * (2 * I_DIM) + i];
    for (int t = 0; t < TSEG; t += 2) {
        float d2 = 0.f, u2 = 0.f, g2 = 0.f, d3 = 0.f, u3 = 0.f, g3 = 0.f;
        if (t + 3 < TSEG) {
            d2 = (float)delta[(size_t)(t0 + t + 2) * (2 * I_DIM) + i];
            u2 = (float)xc[(size_t)(t0 + t + 2) * I_DIM + i];
            g2 = (float)gate[(size_t)(t0 + t + 2) * (2 * I_DIM) + i];
            d3 = (float)delta[(size_t)(t0 + t + 3) * (2 * I_DIM) + i];
            u3 = (float)xc[(size_t)(t0 + t + 3) * I_DIM + i];
            g3 = (float)gate[(size_t)(t0 + t + 3) * (2 * I_DIM) + i];
        }
#pragma unroll
        for (int ss = 0; ss < 2; ++ss) {
            const float d = ss ? d1 : d0;
            const float u = ss ? u1 : u0;
            const float g = ss ? g1 : g0;
            const int tt = t + ss;
            const float du = d * u;
            float y = 0.f;
#pragma unroll
            for (int n = 0; n < 8; ++n) {
                const float a = __expf(d * Ai[n]);
                h[n] = fmaf(h[n], a, du * BCs[tt][half * 8 + n]);
                y = fmaf(h[n], BCs[tt][16 + half * 8 + n], y);
            }
            y += __shfl_xor(y, 1);
            if (half == 0) {
                const float sg = g / (1.f + __expf(-g));
                const float zv = (y + u * Di) * sg;
                const int row = t0 + tt;
                zPh[((size_t)(row >> 4) * (I_DIM >> 5)) * 512 + zb + (size_t)(row & 15) * 8]
                    = (_Float16)zv;
            }
        }
        d0 = d2; u0 = u2; g0 = g2; d1 = d3; u1 = u3; g1 = g3;
    }
}

// ---------------------------------------------------------------------------
extern "C" void kernel_launch(void* const* d_in, const int* in_sizes, int n_in,
                              void* d_out, int out_size, void* d_ws, size_t ws_size,
                              hipStream_t stream)
{
    const float* hs      = (const float*)d_in[0];
    const float* W_in    = (const float*)d_in[1];
    const float* conv_w  = (const float*)d_in[2];
    const float* conv_b  = (const float*)d_in[3];
    const float* W_x     = (const float*)d_in[4];
    const float* W_dt    = (const float*)d_in[5];
    const float* dt_bias = (const float*)d_in[6];
    const float* A_log   = (const float*)d_in[7];
    const float* Dp      = (const float*)d_in[8];
    const float* W_out   = (const float*)d_in[9];
    float* out = (float*)d_out;

    // workspace layout (~223 MB)
    char* p = (char*)d_ws;
    auto alloc = [&](size_t bytes) {
        char* r = p;
        p += (bytes + 255) & ~(size_t)255;
        return r;
    };
    _Float16* proj16 = (_Float16*)alloc((size_t)68 * 1024 * 1024);
    _Float16* xconv16 = (_Float16*)alloc((size_t)LC * I_DIM * 2);  // 32 MB
    float* ssm    = (float*)alloc((size_t)LC * 160 * 4);           // 2.6 MB
    float* xtail  = (float*)alloc((size_t)2 * 3 * I_DIM * 4);
    float* hstate = (float*)alloc((size_t)IN_DIM * 4);
    _Float16* WinPh  = (_Float16*)alloc((size_t)2 * I_DIM * H_DIM * 2);  // 32 MB
    _Float16* WoutPh = (_Float16*)alloc((size_t)H_DIM * I_DIM * 2);      // 16 MB
    _Float16* WdtPh  = (_Float16*)alloc((size_t)I_DIM * R_DIM * 2);
    _Float16* WdtPl  = (_Float16*)alloc((size_t)I_DIM * R_DIM * 2);
    _Float16* WxPh   = (_Float16*)alloc((size_t)256 * I_DIM * 2);
    _Float16* WxPl   = (_Float16*)alloc((size_t)256 * I_DIM * 2);
    _Float16* hsPh   = (_Float16*)alloc((size_t)L_DIM * H_DIM * 2);  // 33.5 MB
    _Float16* zPh    = (_Float16*)alloc((size_t)LC * I_DIM * 2);     // 32 MB

    const dim3 blk(256);
    const int NSSM = R_DIM + 2 * N_DIM;  // 160

    // ---- pack weights + full hs into panel format (once per launch) ----
    pack_bp<<<dim3(2 * I_DIM / 32, H_DIM / 32), dim3(128), 0, stream>>>(
        W_in, WinPh, nullptr, H_DIM, 2 * I_DIM);
    pack_bp<<<dim3(H_DIM / 32, I_DIM / 32), dim3(128), 0, stream>>>(
        W_out, WoutPh, nullptr, I_DIM, H_DIM);
    pack_bp<<<dim3(I_DIM / 32, R_DIM / 32), dim3(128), 0, stream>>>(
        W_dt, WdtPh, WdtPl, R_DIM, I_DIM);
    pack_bp<<<dim3(NSSM / 32, I_DIM / 32), dim3(128), 0, stream>>>(
        W_x, WxPh, WxPl, I_DIM, NSSM);
    pack_ap<<<dim3(L_DIM / 16, H_DIM / 128), blk, 0, stream>>>(
        hs, H_DIM, hsPh, H_DIM);

    for (int c = 0; c < NCHUNK; ++c) {
        const int t0 = c * LC;
        const int first = (c == 0) ? 1 : 0;
        float* out_c = out + (size_t)t0 * H_DIM;
        float* aprod = out_c;                 // scan scratch in out region
        float* hend  = out_c + (size_t)SEG * IN_DIM;  // exact fit: 2*SEG*IN = LC*H
        float* xtA = xtail + (size_t)(c & 1) * 3 * I_DIM;
        float* xtB = xtail + (size_t)((c & 1) ^ 1) * 3 * I_DIM;
        const _Float16* hsPh_c = hsPh + (size_t)(t0 >> 4) * (H_DIM >> 5) * 512;

        // 1) proj(f16) = hs_c @ W_in  (512 blocks; 8x8 supertile per XCD)
        gemm_r256<1><<<dim3(512, 1), dim3(512), 0, stream>>>(
            hsPh_c, WinPh, proj16, 2 * I_DIM, H_DIM, LC / 256, 8, 8, H_DIM, 0);

        // 2) xconv(f16) = silu(dwconv(x_pre) + b); zeroes ssm; saves tail
        conv_silu_kernel<<<dim3((LC / 8) * (I_DIM / 4) / 256), blk, 0, stream>>>(
            proj16, xtA, xtB, conv_w, conv_b, xconv16, ssm, first);

        // 3) ssm = xconv @ W_x  (f16 A direct, B split, split-K x8, atomics)
        gemm_p<0, 3, 0, 1, true, 0><<<dim3(2 * (LC / 128), 8), blk, 0, stream>>>(
            xconv16, I_DIM, nullptr, WxPh, WxPl, ssm, NSSM,
            I_DIM, NSSM, LC / 128, I_DIM / 8, nullptr);

        // 4) delta(f16) = softplus(ssm[:, :R] @ W_dt + dt_bias) -> proj x-half
        gemm_p<1, 0, 1, 1, false, 1><<<dim3(32 * (LC / 128), 1), blk, 0, stream>>>(
            ssm, NSSM, nullptr, WdtPh, WdtPl, proj16, 2 * I_DIM,
            R_DIM, 0, LC / 128, R_DIM, dt_bias);

        // 5) segment-parallel scan; z -> zPh panels
        scan_part1<<<dim3(I_DIM / 128, SEG), blk, 0, stream>>>(
            proj16, ssm, xconv16, A_log, aprod, hend);
        scan_part2<<<dim3(IN_DIM / 256), blk, 0, stream>>>(
            aprod, hend, hstate, first);
        scan_part3<<<dim3(I_DIM / 128, SEG), blk, 0, stream>>>(
            proj16, proj16 + I_DIM, ssm, xconv16, zPh, A_log, Dp, hend);

        // 6) GEMM4 partials (f16): 2 k-slices; 4x4 supertile per XCD
        gemm_r256<1><<<dim3((LC / 256) * (H_DIM / 256), 2), dim3(512), 0, stream>>>(
            zPh, WoutPh, proj16, H_DIM, I_DIM, LC / 256, 4, 4,
            I_DIM / 2, (size_t)LC * H_DIM);

        // 7) out_c = P0+P1
        reduce2_f16_kernel<<<dim3(LC * H_DIM / 2048), blk, 0, stream>>>(
            proj16, out_c);
    }
}

// Round 23
// 955.921 us; speedup vs baseline: 5.9260x; 1.0265x over previous
//
#include <hip/hip_runtime.h>
#include <cmath>
#include <stdint.h>

#define H_DIM 2048
#define I_DIM 4096
#define N_DIM 16
#define R_DIM 128
#define K_CONV 4
#define L_DIM 8192
#define LC 4096                 // chunk length
#define NCHUNK (L_DIM / LC)
#define SEG 64                  // scan segments per chunk
#define TSEG (LC / SEG)         // 64 steps per segment
#define IN_DIM (I_DIM * N_DIM)  // 65536 recurrences

typedef _Float16 f16x8 __attribute__((ext_vector_type(8)));
typedef _Float16 f16x4v __attribute__((ext_vector_type(4)));
typedef float    f32x4 __attribute__((ext_vector_type(4)));

// direct HBM->LDS, 16B per lane; LDS base must be wave-uniform (HW adds lane*16)
__device__ __forceinline__ void gl_lds(const _Float16* g, _Float16* lbase, int lane) {
#if __has_builtin(__builtin_amdgcn_global_load_lds)
    __builtin_amdgcn_global_load_lds(
        (const __attribute__((address_space(1))) void*)g,
        (__attribute__((address_space(3))) void*)lbase, 16, 0, 0);
#else
    *(f16x8*)&lbase[lane * 8] = *(const f16x8*)g;
#endif
}

// ---------------------------------------------------------------------------
// 256x256 panel GEMM (GEMM1 & GEMM4): A direct global->VGPR (panel layout is
// fragment-ordered), B staged in LDS via 3-buffer counted-vmcnt gl_lds.
// 512 threads = 8 waves (4m x 2n), wave tile 64x128, acc[4][8]. BK=32.
// LDS = 48KB. launch_bounds(512,2): acc[4][8] needs >=160 VGPR; (512,4)
// forces 64 VGPR and spills the accumulator (round-19: 8.6 GB scratch
// traffic/dispatch). Do NOT raise this.
// XCD-balanced supertiles: xcd = orig&7 owns an sm x sn tile rectangle
// (sm*sn = gridDim.x/8) -> balanced per-XCD working set (r22: FETCH -33%).
// Steady wait: B(k+1)2 + B(k+2)2 + A(k+1)4 in flight -> vmcnt(8).
// Split-K via blockIdx.y*kchunk, partials at C + y*partStride. OUTF16 store.
// Requires KT = kchunk/32 even and >= 4.
// ---------------------------------------------------------------------------
template <int OUTF16>
__global__ __launch_bounds__(512, 2) void gemm_r256(
    const _Float16* __restrict__ Aph,
    const _Float16* __restrict__ Bph,
    void* __restrict__ Cv, int ldc, int Kd, int gm,
    int sm, int sn,
    int kchunk, size_t partStride)
{
    __shared__ __align__(16) _Float16 Bs[3][8192];  // [buf][16 n-panels]

    const int tid = threadIdx.x;
    // balanced-rectangle XCD decomposition (bijective; grid = 8*sm*sn)
    const int xcd = blockIdx.x & 7;
    const int t   = blockIdx.x >> 3;
    const int gmdiv = gm / sm;
    const int mr = xcd % gmdiv, nr = xcd / gmdiv;
    const int m0 = (mr * sm + (t % sm)) * 256;
    const int n0 = (nr * sn + (t / sm)) * 256;
    const int kbeg = blockIdx.y * kchunk;

    const int w = tid >> 6, l = tid & 63;
    const int wm = w & 3, wn = w >> 2;   // 4m x 2n waves
    const int lr = l & 15, lg = l >> 4;

    const int KP = Kd >> 5;
    const int np0 = n0 >> 4, mp0 = m0 >> 4;

    f32x4 acc[4][8];
#pragma unroll
    for (int a = 0; a < 4; ++a)
#pragma unroll
        for (int b = 0; b < 8; ++b) acc[a][b] = (f32x4){0.f, 0.f, 0.f, 0.f};

    // wave's 4 A row-panels: mp0 + wm*4 + t
    const _Float16* Abase = Aph + ((size_t)(mp0 + wm * 4) * KP) * 512 + (size_t)l * 8;
    const size_t Astride = (size_t)KP * 512;

    f16x8 faA[4], faB[4];

    auto loadA = [&](int k0, f16x8* fa) {
        const size_t ko = (size_t)(k0 >> 5) * 512;
#pragma unroll
        for (int tt = 0; tt < 4; ++tt)
            fa[tt] = *(const f16x8*)(Abase + (size_t)tt * Astride + ko);
    };
    auto stageB = [&](int k0, int p) {   // 2 gl_lds / thread
        const int kp = k0 >> 5;
#pragma unroll
        for (int s = 0; s < 2; ++s) {
            const int st = w + s * 8;
            gl_lds(Bph + ((size_t)(np0 + st) * KP + kp) * 512 + (size_t)l * 8,
                   &Bs[p][st * 512], l);
        }
    };
    auto domfma = [&](int p, f16x8* fa) {
        f16x8 fb[8];
#pragma unroll
        for (int nt = 0; nt < 8; ++nt)
            fb[nt] = *(const f16x8*)&Bs[p][(wn * 8 + nt) * 512 + l * 8];
        __builtin_amdgcn_s_setprio(1);
#pragma unroll
        for (int mt = 0; mt < 4; ++mt)
#pragma unroll
            for (int nt = 0; nt < 8; ++nt)
                acc[mt][nt] = __builtin_amdgcn_mfma_f32_16x16x32_f16(
                    fa[mt], fb[nt], acc[mt][nt], 0, 0, 0);
        __builtin_amdgcn_s_setprio(0);
    };

    const int KT = kchunk >> 5;          // even, >= 4
    stageB(kbeg, 0);
    stageB(kbeg + 32, 1);
    loadA(kbeg, faA);

    int k = 0;
    for (; k + 3 < KT; k += 2) {
        stageB(kbeg + (k + 2) * 32, (k + 2) % 3);
        loadA(kbeg + (k + 1) * 32, faB);
        asm volatile("s_waitcnt vmcnt(8)" ::: "memory");
        __builtin_amdgcn_s_barrier();
        __builtin_amdgcn_sched_barrier(0);
        domfma(k % 3, faA);
        __builtin_amdgcn_s_barrier();

        stageB(kbeg + (k + 3) * 32, (k + 3) % 3);
        loadA(kbeg + (k + 2) * 32, faA);
        asm volatile("s_waitcnt vmcnt(8)" ::: "memory");
        __builtin_amdgcn_s_barrier();
        __builtin_amdgcn_sched_barrier(0);
        domfma((k + 1) % 3, faB);
        __builtin_amdgcn_s_barrier();
    }
    // k == KT-2
    loadA(kbeg + (KT - 1) * 32, faB);
    asm volatile("s_waitcnt vmcnt(4)" ::: "memory");
    __builtin_amdgcn_s_barrier();
    __builtin_amdgcn_sched_barrier(0);
    domfma((KT - 2) % 3, faA);
    __builtin_amdgcn_s_barrier();
    asm volatile("s_waitcnt vmcnt(0)" ::: "memory");
    __builtin_amdgcn_s_barrier();
    __builtin_amdgcn_sched_barrier(0);
    domfma((KT - 1) % 3, faB);

#pragma unroll
    for (int mt = 0; mt < 4; ++mt) {
        const int row = m0 + wm * 64 + mt * 16 + lg * 4;
#pragma unroll
        for (int nt = 0; nt < 8; ++nt) {
            const int col = n0 + wn * 128 + nt * 16 + lr;
#pragma unroll
            for (int j = 0; j < 4; ++j) {
                if (OUTF16) {
                    _Float16* C = (_Float16*)Cv + (size_t)blockIdx.y * partStride;
                    C[(size_t)(row + j) * ldc + col] = (_Float16)acc[mt][nt][j];
                } else {
                    float* C = (float*)Cv + (size_t)blockIdx.y * partStride;
                    C[(size_t)(row + j) * ldc + col] = acc[mt][nt][j];
                }
            }
        }
    }
}

// ---------------------------------------------------------------------------
// out = P0+P1 (f16 partials, f32 out), 8 elems / thread.
// ---------------------------------------------------------------------------
__global__ __launch_bounds__(256) void reduce2_f16_kernel(
    const _Float16* __restrict__ P, float* __restrict__ out)
{
    const size_t idx = ((size_t)blockIdx.x * 256 + threadIdx.x) * 8;
    const size_t S = (size_t)LC * H_DIM;
    const f16x8 a = *(const f16x8*)(P + idx);
    const f16x8 b = *(const f16x8*)(P + S + idx);
    float r[8];
#pragma unroll
    for (int j = 0; j < 8; ++j)
        r[j] = (float)a[j] + (float)b[j];
    *(float4*)(out + idx)     = *(float4*)&r[0];
    *(float4*)(out + idx + 4) = *(float4*)&r[4];
}

// ---------------------------------------------------------------------------
// 128x128 panel GEMM (GEMM2/3), 2-buffer schedule.
// AK=0: fp32 A reg-split. AK=3: f16 A rows, hi-only, no cvt (xconv path).
// ASPLIT/BSPLIT lo-correction; OUTF16: store f16 (non-atomic only).
// ---------------------------------------------------------------------------
template <int EPI, int AK, int ASPLIT, int BSPLIT, bool ATOMIC, int OUTF16>
__global__ __launch_bounds__(256, ASPLIT ? 2 : (BSPLIT ? 3 : 4)) void gemm_p(
    const void* __restrict__ Av, int lda,
    const _Float16* __restrict__ Aph,
    const _Float16* __restrict__ Bph, const _Float16* __restrict__ Bpl,
    void* __restrict__ Cv, int ldc,
    int Kd, int Ncap, int gm, int kchunk,
    const float* __restrict__ bias)
{
    constexpr int S_AH = 0;
    constexpr int S_AL = ASPLIT ? 1 : 0;
    constexpr int S_BH = ASPLIT ? 2 : 1;
    constexpr int S_BL = S_BH + 1;
    constexpr int NSLOT = S_BH + 1 + BSPLIT;
    __shared__ __align__(16) _Float16 Sh[2][NSLOT][4096];

    const int tid = threadIdx.x;
    int bid = blockIdx.x;
    const int q = gridDim.x >> 3;
    bid = (bid & 7) * q + (bid >> 3);
    const int m0 = (bid % gm) * 128;
    const int n0 = (bid / gm) * 128;

    const int kbeg = blockIdx.y * kchunk;
    const int kend = (kbeg + kchunk < Kd) ? (kbeg + kchunk) : Kd;

    const int w = tid >> 6, l = tid & 63;
    const int wm = w & 1, wn = w >> 1;
    const int lr = l & 15, lg = l >> 4;

    const int ar = tid >> 1, ah = tid & 1;
    const int aw0 = (ar >> 4) * 512 + (((ah * 2) * 16 + (ar & 15)) * 8);
    const int aw1 = aw0 + 128;

    const int KP = Kd >> 5;
    const int np0 = n0 >> 4;

    f32x4 acc[4][4];
#pragma unroll
    for (int a = 0; a < 4; ++a)
#pragma unroll
        for (int b = 0; b < 4; ++b) acc[a][b] = (f32x4){0.f, 0.f, 0.f, 0.f};

    float xf[16];
    f16x8 sah[2], sal[2];

    auto issueA = [&](int k0) {
        if (AK == 0) {
            const float* Ap = (const float*)Av + (size_t)(m0 + ar) * lda + k0 + ah * 16;
            *(float4*)&xf[0]  = *(const float4*)(Ap + 0);
            *(float4*)&xf[4]  = *(const float4*)(Ap + 4);
            *(float4*)&xf[8]  = *(const float4*)(Ap + 8);
            *(float4*)&xf[12] = *(const float4*)(Ap + 12);
        } else if (AK == 3) {
            const _Float16* Ap = (const _Float16*)Av + (size_t)(m0 + ar) * lda + k0 + ah * 16;
            sah[0] = *(const f16x8*)(Ap + 0);
            sah[1] = *(const f16x8*)(Ap + 8);
        }
    };
    auto cvtA = [&]() {
        if (AK == 0) {
#pragma unroll
            for (int c2 = 0; c2 < 2; ++c2)
#pragma unroll
                for (int j = 0; j < 8; ++j) {
                    const float xv = xf[c2 * 8 + j];
                    const _Float16 h = (_Float16)xv;
                    sah[c2][j] = h;
                    if (ASPLIT) sal[c2][j] = (_Float16)(xv - (float)h);
                }
        }
    };
    auto writeA = [&](int p) {
        *(f16x8*)&Sh[p][S_AH][aw0] = sah[0];
        *(f16x8*)&Sh[p][S_AH][aw1] = sah[1];
        if (ASPLIT) {
            *(f16x8*)&Sh[p][S_AL][aw0] = sal[0];
            *(f16x8*)&Sh[p][S_AL][aw1] = sal[1];
        }
    };
    auto stageGL = [&](int k0, int p) {
        const int kp = k0 >> 5;
#pragma unroll
        for (int qq = 0; qq < 2; ++qq) {
            const int st = 2 * w + qq;
            const size_t go = ((size_t)(np0 + st) * KP + kp) * 512 + (size_t)l * 8;
            gl_lds(Bph + go, &Sh[p][S_BH][st * 512], l);
            if (BSPLIT) gl_lds(Bpl + go, &Sh[p][S_BL][st * 512], l);
        }
    };
    auto domfma = [&](int b) {
        f16x8 fah[4], fal[4], fbh[4], fbl[4];
#pragma unroll
        for (int t = 0; t < 4; ++t) {
            fah[t] = *(const f16x8*)&Sh[b][S_AH][(wm * 4 + t) * 512 + l * 8];
            if (ASPLIT) fal[t] = *(const f16x8*)&Sh[b][S_AL][(wm * 4 + t) * 512 + l * 8];
            fbh[t] = *(const f16x8*)&Sh[b][S_BH][(wn * 4 + t) * 512 + l * 8];
            if (BSPLIT) fbl[t] = *(const f16x8*)&Sh[b][S_BL][(wn * 4 + t) * 512 + l * 8];
        }
        __builtin_amdgcn_s_setprio(1);
#pragma unroll
        for (int mt = 0; mt < 4; ++mt)
#pragma unroll
            for (int nt = 0; nt < 4; ++nt) {
                f32x4& a = acc[mt][nt];
                a = __builtin_amdgcn_mfma_f32_16x16x32_f16(fah[mt], fbh[nt], a, 0, 0, 0);
                if (BSPLIT)
                    a = __builtin_amdgcn_mfma_f32_16x16x32_f16(fah[mt], fbl[nt], a, 0, 0, 0);
                if (ASPLIT)
                    a = __builtin_amdgcn_mfma_f32_16x16x32_f16(fal[mt], fbh[nt], a, 0, 0, 0);
            }
        __builtin_amdgcn_s_setprio(0);
    };

    issueA(kbeg); cvtA(); writeA(0);
    stageGL(kbeg, 0);
    __syncthreads();
    int p = 0;
    for (int k0 = kbeg; k0 < kend; k0 += 32) {
        const bool more = (k0 + 32 < kend);
        if (more) {
            issueA(k0 + 32);
            stageGL(k0 + 32, p ^ 1);
        }
        domfma(p);
        if (more) { cvtA(); writeA(p ^ 1); }
        __syncthreads();
        p ^= 1;
    }

#pragma unroll
    for (int mt = 0; mt < 4; ++mt) {
        const int row = m0 + wm * 64 + mt * 16 + lg * 4;
#pragma unroll
        for (int nt = 0; nt < 4; ++nt) {
            const int col = n0 + wn * 64 + nt * 16 + lr;
            if (Ncap == 0 || col < Ncap) {
#pragma unroll
                for (int j = 0; j < 4; ++j) {
                    float v = acc[mt][nt][j];
                    if (EPI == 1) {
                        v += bias[col];
                        v = (v > 20.f) ? v : __logf(1.f + __expf(v));
                    }
                    const size_t off = (size_t)(row + j) * ldc + col;
                    if (ATOMIC)      atomicAdd(&((float*)Cv)[off], v);
                    else if (OUTF16) ((_Float16*)Cv)[off] = (_Float16)v;
                    else             ((float*)Cv)[off] = v;
                }
            }
        }
    }
}

// ---------------------------------------------------------------------------
// Pack W [Kd][Nd] fp32 -> f16 B-panels [Nd/16][Kd/32][512]; lo only if Pl.
// ---------------------------------------------------------------------------
__global__ __launch_bounds__(128) void pack_bp(
    const float* __restrict__ W, _Float16* __restrict__ Ph,
    _Float16* __restrict__ Pl, int Kd, int Nd)
{
    __shared__ float t[32][33];
    const int tid = threadIdx.x;
    const int n0 = blockIdx.x * 32, k0 = blockIdx.y * 32;
#pragma unroll
    for (int h = 0; h < 2; ++h) {
        const int qd = tid + h * 128;
        const int kk = qd >> 3, qq = qd & 7;
        *(float4*)&t[kk][qq * 4] = *(const float4*)(W + (size_t)(k0 + kk) * Nd + n0 + qq * 4);
    }
    __syncthreads();
    const int c = tid >> 5, nn = tid & 31;
    const int np = (n0 + nn) >> 4;
    const int r  = nn & 15;
    const int kp = k0 >> 5;
    const size_t base = ((size_t)np * (Kd >> 5) + kp) * 512 + (c * 16 + r) * 8;
    f16x8 vh, vl;
#pragma unroll
    for (int j = 0; j < 8; ++j) {
        const float v = t[c * 8 + j][nn];
        const _Float16 h = (_Float16)v;
        vh[j] = h;
        vl[j] = (_Float16)(v - (float)h);
    }
    *(f16x8*)&Ph[base] = vh;
    if (Pl) *(f16x8*)&Pl[base] = vl;
}

// ---------------------------------------------------------------------------
// Pack A fp32 [M][K] row-major -> hi f16 A-panels [M/16][K/32][512].
// ---------------------------------------------------------------------------
__global__ __launch_bounds__(256) void pack_ap(
    const float* __restrict__ A, int lda,
    _Float16* __restrict__ Ph, int Kd)
{
    const int tid = threadIdx.x;
    const int mp = blockIdx.x;
    const int r = tid >> 4, c8 = tid & 15;
    const int k0 = blockIdx.y * 128 + c8 * 8;
    const float* Ap = A + (size_t)(mp * 16 + r) * lda + k0;
    const float4 v0 = *(const float4*)Ap;
    const float4 v1 = *(const float4*)(Ap + 4);
    const float x[8] = {v0.x, v0.y, v0.z, v0.w, v1.x, v1.y, v1.z, v1.w};
    f16x8 vh;
#pragma unroll
    for (int j = 0; j < 8; ++j) vh[j] = (_Float16)x[j];
    const int kp = k0 >> 5;
    const int c  = (k0 >> 3) & 3;
    const size_t base = ((size_t)mp * (Kd >> 5) + kp) * 512 + (c * 16 + r) * 8;
    *(f16x8*)&Ph[base] = vh;
}

// ---------------------------------------------------------------------------
// Causal depthwise conv (K=4) + bias + silu (4ch x 8t / thread); zeroes ssm.
// proj (x-half) f16 ld 2I; xconv written f16. Tail saved f32.
// ---------------------------------------------------------------------------
__global__ __launch_bounds__(256) void conv_silu_kernel(
    const _Float16* __restrict__ proj,
    const float* __restrict__ xtail_in,
    float* __restrict__ xtail_out,
    const float* __restrict__ w,
    const float* __restrict__ b,
    _Float16* __restrict__ xconv,
    float* __restrict__ ssm,
    int first)
{
    const int gid = blockIdx.x * 256 + threadIdx.x;
    if (gid < (LC * 160) / 4)
        *(float4*)(ssm + (size_t)gid * 4) = make_float4(0.f, 0.f, 0.f, 0.f);

    const int i4 = gid & (I_DIM / 4 - 1);
    const int t8 = gid >> 10;
    const int i = i4 * 4;
    const int tt0 = t8 * 8;

    const float4 w0 = *(const float4*)(w + (size_t)(i + 0) * 4);
    const float4 w1 = *(const float4*)(w + (size_t)(i + 1) * 4);
    const float4 w2 = *(const float4*)(w + (size_t)(i + 2) * 4);
    const float4 w3 = *(const float4*)(w + (size_t)(i + 3) * 4);
    const float4 bb = *(const float4*)(b + i);

    auto ldrow = [&](int row) -> float4 {
        const f16x4v v = *(const f16x4v*)(proj + (size_t)row * (2 * I_DIM) + i);
        return make_float4((float)v[0], (float)v[1], (float)v[2], (float)v[3]);
    };

    float4 r[11];
    if (tt0 >= 3) {
#pragma unroll
        for (int s = 0; s < 11; ++s) r[s] = ldrow(tt0 - 3 + s);
    } else {
#pragma unroll
        for (int s = 0; s < 3; ++s)
            r[s] = first ? make_float4(0.f, 0.f, 0.f, 0.f)
                         : *(const float4*)(xtail_in + (size_t)s * I_DIM + i);
#pragma unroll
        for (int s = 3; s < 11; ++s) r[s] = ldrow(tt0 - 3 + s);
    }

#pragma unroll
    for (int s = 0; s < 8; ++s) {
        float4 y = bb;
        y.x = fmaf(w0.x, r[s].x, y.x); y.x = fmaf(w0.y, r[s+1].x, y.x);
        y.x = fmaf(w0.z, r[s+2].x, y.x); y.x = fmaf(w0.w, r[s+3].x, y.x);
        y.y = fmaf(w1.x, r[s].y, y.y); y.y = fmaf(w1.y, r[s+1].y, y.y);
        y.y = fmaf(w1.z, r[s+2].y, y.y); y.y = fmaf(w1.w, r[s+3].y, y.y);
        y.z = fmaf(w2.x, r[s].z, y.z); y.z = fmaf(w2.y, r[s+1].z, y.z);
        y.z = fmaf(w2.z, r[s+2].z, y.z); y.z = fmaf(w2.w, r[s+3].z, y.z);
        y.w = fmaf(w3.x, r[s].w, y.w); y.w = fmaf(w3.y, r[s+1].w, y.w);
        y.w = fmaf(w3.z, r[s+2].w, y.w); y.w = fmaf(w3.w, r[s+3].w, y.w);
        y.x = y.x / (1.f + __expf(-y.x));
        y.y = y.y / (1.f + __expf(-y.y));
        y.z = y.z / (1.f + __expf(-y.z));
        y.w = y.w / (1.f + __expf(-y.w));
        f16x4v o;
        o[0] = (_Float16)y.x; o[1] = (_Float16)y.y;
        o[2] = (_Float16)y.z; o[3] = (_Float16)y.w;
        *(f16x4v*)(xconv + (size_t)(tt0 + s) * I_DIM + i) = o;
    }

    if (tt0 == LC - 8) {
#pragma unroll
        for (int qq = 0; qq < 3; ++qq)
            *(float4*)(xtail_out + (size_t)qq * I_DIM + i) = r[8 + qq];
    }
}

// ---------------------------------------------------------------------------
// Segment-parallel scan. delta/gate f16 (ld 2I); u (xc) f16.
// Segment summaries (aprod/hend/hstart) stored f16 (chain arithmetic f32).
// ---------------------------------------------------------------------------
__global__ __launch_bounds__(256) void scan_part1(
    const _Float16* __restrict__ delta,
    const float* __restrict__ ssm,
    const _Float16* __restrict__ xc,
    const float* __restrict__ A_log,
    _Float16* __restrict__ aprod,
    _Float16* __restrict__ hend)
{
    __shared__ float Bs[TSEG][16];
    const int tid = threadIdx.x;
    const int i = blockIdx.x * 128 + (tid >> 1);
    const int half = tid & 1;
    const int seg = blockIdx.y;
    const int t0 = seg * TSEG;

    {
        const int tt = tid >> 2, c = (tid & 3) * 4;
        *(float4*)&Bs[tt][c] = *(const float4*)&ssm[(size_t)(t0 + tt) * 160 + 128 + c];
    }
    __syncthreads();

    float Ai[8], h[8], ap[8];
    {
        const float4 a0 = *(const float4*)&A_log[(size_t)i * 16 + half * 8];
        const float4 a1 = *(const float4*)&A_log[(size_t)i * 16 + half * 8 + 4];
        const float al[8] = {a0.x, a0.y, a0.z, a0.w, a1.x, a1.y, a1.z, a1.w};
#pragma unroll
        for (int n = 0; n < 8; ++n) { Ai[n] = -expf(al[n]); h[n] = 0.f; ap[n] = 1.f; }
    }

    float d0 = (float)delta[(size_t)t0 * (2 * I_DIM) + i];
    float u0 = (float)xc[(size_t)t0 * I_DIM + i];
    float d1 = (float)delta[(size_t)(t0 + 1) * (2 * I_DIM) + i];
    float u1 = (float)xc[(size_t)(t0 + 1) * I_DIM + i];
    for (int t = 0; t < TSEG; t += 2) {
        float d2 = 0.f, u2 = 0.f, d3 = 0.f, u3 = 0.f;
        if (t + 3 < TSEG) {
            d2 = (float)delta[(size_t)(t0 + t + 2) * (2 * I_DIM) + i];
            u2 = (float)xc[(size_t)(t0 + t + 2) * I_DIM + i];
            d3 = (float)delta[(size_t)(t0 + t + 3) * (2 * I_DIM) + i];
            u3 = (float)xc[(size_t)(t0 + t + 3) * I_DIM + i];
        }
        {
            const float du = d0 * u0;
#pragma unroll
            for (int n = 0; n < 8; ++n) {
                const float a = __expf(d0 * Ai[n]);
                h[n] = fmaf(h[n], a, du * Bs[t][half * 8 + n]);
                ap[n] *= a;
            }
        }
        {
            const float du = d1 * u1;
#pragma unroll
            for (int n = 0; n < 8; ++n) {
                const float a = __expf(d1 * Ai[n]);
                h[n] = fmaf(h[n], a, du * Bs[t + 1][half * 8 + n]);
                ap[n] *= a;
            }
        }
        d0 = d2; u0 = u2; d1 = d3; u1 = u3;
    }

    const size_t base = (size_t)seg * IN_DIM + (size_t)i * 16 + half * 8;
    f16x8 va, vh;
#pragma unroll
    for (int n = 0; n < 8; ++n) {
        va[n] = (_Float16)ap[n];
        vh[n] = (_Float16)h[n];
    }
    *(f16x8*)&aprod[base] = va;
    *(f16x8*)&hend[base]  = vh;
}

__global__ __launch_bounds__(256) void scan_part2(
    const _Float16* __restrict__ aprod,
    _Float16* __restrict__ hend,
    float* __restrict__ hstate,
    int first)
{
    const int gid = blockIdx.x * 256 + threadIdx.x;
    float h = first ? 0.f : hstate[gid];
    for (int s = 0; s < SEG; ++s) {
        const size_t idx = (size_t)s * IN_DIM + gid;
        const float ap = (float)aprod[idx];
        const float he = (float)hend[idx];
        hend[idx] = (_Float16)h;
        h = fmaf(ap, h, he);
    }
    hstate[gid] = h;
}

// Phase 3: re-run segment from h_start (f16); z (f16) in GEMM4 A-panel layout.
__global__ __launch_bounds__(256) void scan_part3(
    const _Float16* __restrict__ delta,
    const _Float16* __restrict__ gate,
    const float* __restrict__ ssm,
    const _Float16* __restrict__ xc,
    _Float16* __restrict__ zPh,
    const float* __restrict__ A_log,
    const float* __restrict__ Dp,
    const _Float16* __restrict__ hstart)  // [SEG][I][N] f16
{
    __shared__ float BCs[TSEG][32];
    const int tid = threadIdx.x;
    const int i = blockIdx.x * 128 + (tid >> 1);
    const int half = tid & 1;
    const int seg = blockIdx.y;
    const int t0 = seg * TSEG;

    {
        const int tt = tid >> 2, c = (tid & 3) * 8;
        *(float4*)&BCs[tt][c]     = *(const float4*)&ssm[(size_t)(t0 + tt) * 160 + 128 + c];
        *(float4*)&BCs[tt][c + 4] = *(const float4*)&ssm[(size_t)(t0 + tt) * 160 + 132 + c];
    }
    __syncthreads();

    float Ai[8], h[8];
    {
        const float4 a0 = *(const float4*)&A_log[(size_t)i * 16 + half * 8];
        const float4 a1 = *(const float4*)&A_log[(size_t)i * 16 + half * 8 + 4];
        const float al[8] = {a0.x, a0.y, a0.z, a0.w, a1.x, a1.y, a1.z, a1.w};
#pragma unroll
        for (int n = 0; n < 8; ++n) Ai[n] = -expf(al[n]);
        const size_t base = (size_t)seg * IN_DIM + (size_t)i * 16 + half * 8;
        const f16x8 h0 = *(const f16x8*)&hstart[base];
#pragma unroll
        for (int n = 0; n < 8; ++n) h[n] = (float)h0[n];
    }
    const float Di = Dp[i];

    const int kp = i >> 5, cc = (i >> 3) & 3, jj = i & 7;
    const size_t zb = (size_t)kp * 512 + (size_t)cc * 128 + jj;

    float d0 = (float)delta[(size_t)t0 * (2 * I_DIM) + i];
    float u0 = (float)xc[(size_t)t0 * I_DIM + i];
    float g0 = (float)gate[(size_t)t0 * (2 * I_DIM) + i];
    float d1 = (float)delta[(size_t)(t0 + 1) * (2 * I_DIM) + i];
    float u1 = (float)xc[(size_t)(t0 + 1) * I_DIM + i];
    float g1 = (float)gate[(size_t)(t0 + 1) * (2 * I_DIM) + i];
    for (int t = 0; t < TSEG; t += 2) {
        float d2 = 0.f, u2 = 0.f, g2 = 0.f, d3 = 0.f, u3 = 0.f, g3 = 0.f;
        if (t + 3 < TSEG) {
            d2 = (float)delta[(size_t)(t0 + t + 2) * (2 * I_DIM) + i];
            u2 = (float)xc[(size_t)(t0 + t + 2) * I_DIM + i];
            g2 = (float)gate[(size_t)(t0 + t + 2) * (2 * I_DIM) + i];
            d3 = (float)delta[(size_t)(t0 + t + 3) * (2 * I_DIM) + i];
            u3 = (float)xc[(size_t)(t0 + t + 3) * I_DIM + i];
            g3 = (float)gate[(size_t)(t0 + t + 3) * (2 * I_DIM) + i];
        }
#pragma unroll
        for (int ss = 0; ss < 2; ++ss) {
            const float d = ss ? d1 : d0;
            const float u = ss ? u1 : u0;
            const float g = ss ? g1 : g0;
            const int tt = t + ss;
            const float du = d * u;
            float y = 0.f;
#pragma unroll
            for (int n = 0; n < 8; ++n) {
                const float a = __expf(d * Ai[n]);
                h[n] = fmaf(h[n], a, du * BCs[tt][half * 8 + n]);
                y = fmaf(h[n], BCs[tt][16 + half * 8 + n], y);
            }
            y += __shfl_xor(y, 1);
            if (half == 0) {
                const float sg = g / (1.f + __expf(-g));
                const float zv = (y + u * Di) * sg;
                const int row = t0 + tt;
                zPh[((size_t)(row >> 4) * (I_DIM >> 5)) * 512 + zb + (size_t)(row & 15) * 8]
                    = (_Float16)zv;
            }
        }
        d0 = d2; u0 = u2; g0 = g2; d1 = d3; u1 = u3; g1 = g3;
    }
}

// ---------------------------------------------------------------------------
extern "C" void kernel_launch(void* const* d_in, const int* in_sizes, int n_in,
                              void* d_out, int out_size, void* d_ws, size_t ws_size,
                              hipStream_t stream)
{
    const float* hs      = (const float*)d_in[0];
    const float* W_in    = (const float*)d_in[1];
    const float* conv_w  = (const float*)d_in[2];
    const float* conv_b  = (const float*)d_in[3];
    const float* W_x     = (const float*)d_in[4];
    const float* W_dt    = (const float*)d_in[5];
    const float* dt_bias = (const float*)d_in[6];
    const float* A_log   = (const float*)d_in[7];
    const float* Dp      = (const float*)d_in[8];
    const float* W_out   = (const float*)d_in[9];
    float* out = (float*)d_out;

    // workspace layout (~223 MB)
    char* p = (char*)d_ws;
    auto alloc = [&](size_t bytes) {
        char* r = p;
        p += (bytes + 255) & ~(size_t)255;
        return r;
    };
    _Float16* proj16 = (_Float16*)alloc((size_t)68 * 1024 * 1024);
    _Float16* xconv16 = (_Float16*)alloc((size_t)LC * I_DIM * 2);  // 32 MB
    float* ssm    = (float*)alloc((size_t)LC * 160 * 4);           // 2.6 MB
    float* xtail  = (float*)alloc((size_t)2 * 3 * I_DIM * 4);
    float* hstate = (float*)alloc((size_t)IN_DIM * 4);
    _Float16* WinPh  = (_Float16*)alloc((size_t)2 * I_DIM * H_DIM * 2);  // 32 MB
    _Float16* WoutPh = (_Float16*)alloc((size_t)H_DIM * I_DIM * 2);      // 16 MB
    _Float16* WdtPh  = (_Float16*)alloc((size_t)I_DIM * R_DIM * 2);
    _Float16* WdtPl  = (_Float16*)alloc((size_t)I_DIM * R_DIM * 2);
    _Float16* WxPh   = (_Float16*)alloc((size_t)256 * I_DIM * 2);
    _Float16* WxPl   = (_Float16*)alloc((size_t)256 * I_DIM * 2);
    _Float16* hsPh   = (_Float16*)alloc((size_t)L_DIM * H_DIM * 2);  // 33.5 MB
    _Float16* zPh    = (_Float16*)alloc((size_t)LC * I_DIM * 2);     // 32 MB

    const dim3 blk(256);
    const int NSSM = R_DIM + 2 * N_DIM;  // 160

    // ---- pack weights + full hs into panel format (once per launch) ----
    pack_bp<<<dim3(2 * I_DIM / 32, H_DIM / 32), dim3(128), 0, stream>>>(
        W_in, WinPh, nullptr, H_DIM, 2 * I_DIM);
    pack_bp<<<dim3(H_DIM / 32, I_DIM / 32), dim3(128), 0, stream>>>(
        W_out, WoutPh, nullptr, I_DIM, H_DIM);
    pack_bp<<<dim3(I_DIM / 32, R_DIM / 32), dim3(128), 0, stream>>>(
        W_dt, WdtPh, WdtPl, R_DIM, I_DIM);
    pack_bp<<<dim3(NSSM / 32, I_DIM / 32), dim3(128), 0, stream>>>(
        W_x, WxPh, WxPl, I_DIM, NSSM);
    pack_ap<<<dim3(L_DIM / 16, H_DIM / 128), blk, 0, stream>>>(
        hs, H_DIM, hsPh, H_DIM);

    for (int c = 0; c < NCHUNK; ++c) {
        const int t0 = c * LC;
        const int first = (c == 0) ? 1 : 0;
        float* out_c = out + (size_t)t0 * H_DIM;
        // scan scratch (f16) in the out-chunk region: 2*SEG*IN*2B = 16.7 MB
        // of the 33.5 MB chunk -> fits with slack.
        _Float16* aprod = (_Float16*)out_c;
        _Float16* hend  = aprod + (size_t)SEG * IN_DIM;
        float* xtA = xtail + (size_t)(c & 1) * 3 * I_DIM;
        float* xtB = xtail + (size_t)((c & 1) ^ 1) * 3 * I_DIM;
        const _Float16* hsPh_c = hsPh + (size_t)(t0 >> 4) * (H_DIM >> 5) * 512;

        // 1) proj(f16) = hs_c @ W_in  (512 blocks; 8x8 supertile per XCD)
        gemm_r256<1><<<dim3(512, 1), dim3(512), 0, stream>>>(
            hsPh_c, WinPh, proj16, 2 * I_DIM, H_DIM, LC / 256, 8, 8, H_DIM, 0);

        // 2) xconv(f16) = silu(dwconv(x_pre) + b); zeroes ssm; saves tail
        conv_silu_kernel<<<dim3((LC / 8) * (I_DIM / 4) / 256), blk, 0, stream>>>(
            proj16, xtA, xtB, conv_w, conv_b, xconv16, ssm, first);

        // 3) ssm = xconv @ W_x  (f16 A direct, B split, split-K x8, atomics)
        gemm_p<0, 3, 0, 1, true, 0><<<dim3(2 * (LC / 128), 8), blk, 0, stream>>>(
            xconv16, I_DIM, nullptr, WxPh, WxPl, ssm, NSSM,
            I_DIM, NSSM, LC / 128, I_DIM / 8, nullptr);

        // 4) delta(f16) = softplus(ssm[:, :R] @ W_dt + dt_bias) -> proj x-half
        gemm_p<1, 0, 1, 1, false, 1><<<dim3(32 * (LC / 128), 1), blk, 0, stream>>>(
            ssm, NSSM, nullptr, WdtPh, WdtPl, proj16, 2 * I_DIM,
            R_DIM, 0, LC / 128, R_DIM, dt_bias);

        // 5) segment-parallel scan (f16 summaries); z -> zPh panels
        scan_part1<<<dim3(I_DIM / 128, SEG), blk, 0, stream>>>(
            proj16, ssm, xconv16, A_log, aprod, hend);
        scan_part2<<<dim3(IN_DIM / 256), blk, 0, stream>>>(
            aprod, hend, hstate, first);
        scan_part3<<<dim3(I_DIM / 128, SEG), blk, 0, stream>>>(
            proj16, proj16 + I_DIM, ssm, xconv16, zPh, A_log, Dp, hend);

        // 6) GEMM4 partials (f16): 2 k-slices; 4x4 supertile per XCD
        gemm_r256<1><<<dim3((LC / 256) * (H_DIM / 256), 2), dim3(512), 0, stream>>>(
            zPh, WoutPh, proj16, H_DIM, I_DIM, LC / 256, 4, 4,
            I_DIM / 2, (size_t)LC * H_DIM);

        // 7) out_c = P0+P1
        reduce2_f16_kernel<<<dim3(LC * H_DIM / 2048), blk, 0, stream>>>(
            proj16, out_c);
    }
}